// Round 3
// baseline (2183.498 us; speedup 1.0000x reference)
//
#include <hip/hip_runtime.h>
#include <math.h>

#define NB   256
#define NN   1024
#define ND   64
#define NSL  8
#define NHID 128
#define N_SINK 8
#define N_MESH 4
#define F_LR  3.0f
#define F_EPS 1e-8f

// ---------------------------------------------------------------- k_pre
// x = LN(inputs)*g+b ; kk = |x@Wk^T|^2 ; wilog = x . wi_w + wi_b
__global__ __launch_bounds__(256) void k_pre(
    const float* __restrict__ inp, const float* __restrict__ Wk,
    const float* __restrict__ lng, const float* __restrict__ lnb,
    const float* __restrict__ wiw, const float* __restrict__ wib,
    float* __restrict__ xout, float* __restrict__ kkout, float* __restrict__ wilog) {
  __shared__ __align__(16) float xs[4][64];
  int wv = threadIdx.x >> 6, ln = threadIdx.x & 63;
  size_t row = (size_t)blockIdx.x * 4 + wv;        // < 262144
  float xi = inp[row * 64 + ln];
  float s1 = xi, s2 = xi * xi;
  #pragma unroll
  for (int m = 32; m >= 1; m >>= 1) { s1 += __shfl_xor(s1, m, 64); s2 += __shfl_xor(s2, m, 64); }
  float mean = s1 * (1.f / 64.f);
  float var  = s2 * (1.f / 64.f) - mean * mean;
  float xn = (xi - mean) * rsqrtf(var + 1e-5f) * lng[ln] + lnb[ln];
  xs[wv][ln] = xn;
  xout[row * 64 + ln] = xn;
  float wl = xn * wiw[ln];
  #pragma unroll
  for (int m = 32; m >= 1; m >>= 1) wl += __shfl_xor(wl, m, 64);
  __syncthreads();
  const float4* w4 = (const float4*)(Wk + ln * 64);
  const float4* x4 = (const float4*)xs[wv];
  float ko = 0.f;
  #pragma unroll
  for (int c = 0; c < 16; ++c) {
    float4 a = w4[c], xv = x4[c];
    ko += a.x * xv.x + a.y * xv.y + a.z * xv.z + a.w * xv.w;
  }
  float kk = ko * ko;
  #pragma unroll
  for (int m = 32; m >= 1; m >>= 1) kk += __shfl_xor(kk, m, 64);
  if (ln == 0) { kkout[row] = kk; wilog[row] = wl + wib[0]; }
}

// ---------------------------------------------------------------- helpers
__device__ __forceinline__ void wave_max8(float* a) {
  #pragma unroll
  for (int m = 32; m >= 1; m >>= 1) {
    #pragma unroll
    for (int j = 0; j < 8; ++j) a[j] = fmaxf(a[j], __shfl_xor(a[j], m, 64));
  }
}
__device__ __forceinline__ void wave_sum8(float* a) {
  #pragma unroll
  for (int m = 32; m >= 1; m >>= 1) {
    #pragma unroll
    for (int j = 0; j < 8; ++j) a[j] += __shfl_xor(a[j], m, 64);
  }
}

// ---------------------------------------------------------------- k_mega
// One block per batch. Does: slots init, log_a, then 3x {slotpre, MESH+sinkhorn,
// updates, GRU+FF} with slots/attn resident in LDS. Outputs written at the end.
__global__ __launch_bounds__(1024, 4) void k_mega(
    const float* __restrict__ noise, const float* __restrict__ mu,
    const float* __restrict__ sigma,
    const float* __restrict__ xg, const float* __restrict__ kkg,
    const float* __restrict__ wilogg,
    const float* __restrict__ Wq, const float* __restrict__ Wk,
    const float* __restrict__ Wv,
    const float* __restrict__ wih, const float* __restrict__ whh,
    const float* __restrict__ bih, const float* __restrict__ bhh,
    const float* __restrict__ fc1w, const float* __restrict__ fc1b,
    const float* __restrict__ fc2w, const float* __restrict__ fc2b,
    const float* __restrict__ lns_g, const float* __restrict__ lns_b,
    const float* __restrict__ lnf_g, const float* __restrict__ lnf_b,
    const float* __restrict__ wsw, const float* __restrict__ wsb,
    float* __restrict__ out_slots, float* __restrict__ out_pos,
    float* __restrict__ out_attn) {
  __shared__ __align__(16) float slot_lds[8][64];
  __shared__ __align__(16) float sn[8][64];      // slot LN result; later: updates row
  __shared__ __align__(16) float qsh[8][64];
  __shared__ __align__(16) float qs[8][64];
  __shared__ __align__(16) float updl[8][64];
  __shared__ __align__(16) float ys[8][64];
  __shared__ __align__(16) float rs[8][128];
  __shared__ __align__(16) union {
    float uhist[N_SINK][NN];    // phase B
    float part[16][8][64];      // phase C
  } U;
  __shared__ __align__(16) float as_[8][NN];     // attn (transposed), 32 KB
  __shared__ float redm[16][8], reds[16][8];
  __shared__ float vbc[8], vhist[N_SINK][8];
  __shared__ float bmv[8], q2s[8], lbs[8];
  __shared__ float redf[16], bcf[1];

  int b = blockIdx.x, tid = threadIdx.x;
  int wv = tid >> 6, ln = tid & 63;

  // ---- slots init ----
  if (tid < 512) {
    slot_lds[tid >> 6][ln] = mu[ln] + (fabsf(sigma[ln]) + F_EPS) * noise[(size_t)b * 512 + tid];
  }
  // ---- la = log(8*softmax(wilog)+eps), block-wide ----
  float wl = wilogg[(size_t)b * NN + tid];
  float m0 = wl;
  #pragma unroll
  for (int s = 32; s >= 1; s >>= 1) m0 = fmaxf(m0, __shfl_xor(m0, s, 64));
  if (ln == 0) redf[wv] = m0;
  __syncthreads();
  if (tid == 0) { float a = redf[0]; for (int w = 1; w < 16; ++w) a = fmaxf(a, redf[w]); bcf[0] = a; }
  __syncthreads();
  m0 = bcf[0];
  float e0 = expf(wl - m0), se0 = e0;
  #pragma unroll
  for (int s = 32; s >= 1; s >>= 1) se0 += __shfl_xor(se0, s, 64);
  __syncthreads();
  if (ln == 0) redf[wv] = se0;
  __syncthreads();
  if (tid == 0) { float a = 0.f; for (int w = 0; w < 16; ++w) a += redf[w]; bcf[0] = a; }
  __syncthreads();
  float la = logf(8.f * e0 / bcf[0] + F_EPS);
  float kk = kkg[(size_t)b * NN + tid];
  const float4* xrow4 = (const float4*)(xg + ((size_t)b * NN + tid) * ND);

  float u = 0.f, v[8];

  for (int it = 0; it < 3; ++it) {
    // ================= phase A: slotpre =================
    if (wv < 8) {
      float x = slot_lds[wv][ln];
      float s1 = x, s2 = x * x;
      #pragma unroll
      for (int m = 32; m >= 1; m >>= 1) { s1 += __shfl_xor(s1, m, 64); s2 += __shfl_xor(s2, m, 64); }
      float mean = s1 * (1.f / 64.f);
      float var  = s2 * (1.f / 64.f) - mean * mean;
      float xn = (x - mean) * rsqrtf(var + 1e-5f) * lns_g[ln] + lns_b[ln];
      sn[wv][ln] = xn;
      float wlg = xn * wsw[ln];
      #pragma unroll
      for (int m = 32; m >= 1; m >>= 1) wlg += __shfl_xor(wlg, m, 64);
      if (ln == 0) bmv[wv] = wlg + wsb[0];
    }
    __syncthreads();
    if (wv < 8) {
      const float4* w4 = (const float4*)(Wq + ln * 64);
      const float4* x4 = (const float4*)sn[wv];
      float q = 0.f;
      #pragma unroll
      for (int c = 0; c < 16; ++c) {
        float4 a = w4[c], xv = x4[c];
        q += a.x * xv.x + a.y * xv.y + a.z * xv.z + a.w * xv.w;
      }
      qsh[wv][ln] = q;
      float q2 = q * q;
      #pragma unroll
      for (int m = 32; m >= 1; m >>= 1) q2 += __shfl_xor(q2, m, 64);
      if (ln == 0) q2s[wv] = q2;
    }
    if (tid >= 512 && tid < 520) {   // lbs from bmv (ready after prev barrier)
      int j = tid - 512;
      float mx = bmv[0];
      #pragma unroll
      for (int jj = 1; jj < 8; ++jj) mx = fmaxf(mx, bmv[jj]);
      float ss = 0.f;
      #pragma unroll
      for (int jj = 0; jj < 8; ++jj) ss += expf(bmv[jj] - mx);
      lbs[j] = logf(8.f * expf(bmv[j] - mx) / ss + F_EPS);
    }
    __syncthreads();
    if (wv < 8) {
      float qt = 0.f;
      for (int o = 0; o < 64; ++o) qt = fmaf(qsh[wv][o], Wk[o * 64 + ln], qt);
      qs[wv][ln] = qt;
    }
    __syncthreads();

    // ================= phase B: MESH + sinkhorn =================
    float Know[8];
    {
      float dot[8];
      #pragma unroll
      for (int j = 0; j < 8; ++j) dot[j] = 0.f;
      #pragma unroll 4
      for (int c = 0; c < 16; ++c) {
        float4 xv = xrow4[c];
        #pragma unroll
        for (int j = 0; j < 8; ++j) {
          const float4 qv = *(const float4*)&qs[j][c * 4];
          dot[j] += xv.x * qv.x + xv.y * qv.y + xv.z * qv.z + xv.w * qv.w;
        }
      }
      #pragma unroll
      for (int j = 0; j < 8; ++j) {
        float d2 = kk + q2s[j] - 2.f * dot[j];
        Know[j] = -sqrtf(fmaxf(d2, 1e-12f));
      }
    }
    for (int phase = 0; phase <= N_MESH; ++phase) {
      if (phase < N_MESH) {
        #pragma unroll
        for (int j = 0; j < 8; ++j) v[j] = 0.f;
      }
      // ---- forward: 8 sinkhorn iterations ----
      for (int t = 0; t < N_SINK; ++t) {
        // u-step (row LSE, thread-local)
        float mx = -3.4e38f;
        #pragma unroll
        for (int j = 0; j < 8; ++j) mx = fmaxf(mx, Know[j] + v[j]);
        float se = 0.f;
        #pragma unroll
        for (int j = 0; j < 8; ++j) se += expf(Know[j] + v[j] - mx);
        u = la - (mx + logf(se));
        U.uhist[t][tid] = u;
        // v-step: fused col-LSE (per-wave LSE, cross-wave merge)
        float mm[8], pp[8];
        #pragma unroll
        for (int j = 0; j < 8; ++j) mm[j] = Know[j] + u;
        wave_max8(mm);
        #pragma unroll
        for (int j = 0; j < 8; ++j) pp[j] = expf(Know[j] + u - mm[j]);
        wave_sum8(pp);
        if (ln == 0) {
          #pragma unroll
          for (int j = 0; j < 8; ++j) { redm[wv][j] = mm[j]; reds[wv][j] = pp[j]; }
        }
        __syncthreads();
        if (tid < 8) {
          float M = redm[0][tid];
          #pragma unroll
          for (int w = 1; w < 16; ++w) M = fmaxf(M, redm[w][tid]);
          float S = 0.f;
          #pragma unroll
          for (int w = 0; w < 16; ++w) S += reds[w][tid] * expf(redm[w][tid] - M);
          float vj = lbs[tid] - (M + logf(S));
          vbc[tid] = vj; vhist[t][tid] = vj;
        }
        __syncthreads();
        #pragma unroll
        for (int j = 0; j < 8; ++j) v[j] = vbc[j];
      }
      if (phase == N_MESH) break;

      // ---- backward: dH/dK ----
      float lbr[8];
      #pragma unroll
      for (int j = 0; j < 8; ++j) lbr[j] = lbs[j];
      float Kbar[8], vbar[8], ubarT;
      {
        float cs[8], gsum = 0.f;
        #pragma unroll
        for (int j = 0; j < 8; ++j) {
          float P  = expf(Know[j] + u + v[j]);
          float pe = P + F_EPS;
          float G  = -(logf(pe) + P / pe);
          float gp = G * P;
          Kbar[j] = gp; cs[j] = gp; gsum += gp;
        }
        ubarT = gsum;
        wave_sum8(cs);
        if (ln == 0) {
          #pragma unroll
          for (int j = 0; j < 8; ++j) reds[wv][j] = cs[j];
        }
        __syncthreads();
        if (tid < 8) {
          float S = 0.f;
          #pragma unroll
          for (int w = 0; w < 16; ++w) S += reds[w][tid];
          vbc[tid] = S;
        }
        __syncthreads();
        #pragma unroll
        for (int j = 0; j < 8; ++j) vbar[j] = vbc[j];
      }
      for (int t = N_SINK - 1; t >= 0; --t) {
        float ut = U.uhist[t][tid];
        float dsum = (t == N_SINK - 1) ? ubarT : 0.f;
        #pragma unroll
        for (int j = 0; j < 8; ++j) {
          float w  = expf(Know[j] + ut + vhist[t][j] - lbr[j]);
          float vw = vbar[j] * w;
          Kbar[j] -= vw; dsum -= vw;
        }
        float zs[8];
        #pragma unroll
        for (int j = 0; j < 8; ++j) {
          float vprev = (t > 0) ? vhist[t - 1][j] : 0.f;
          float z  = expf(Know[j] + vprev + ut - la);
          float uz = dsum * z;
          Kbar[j] -= uz; zs[j] = uz;
        }
        if (t > 0) {
          wave_sum8(zs);
          if (ln == 0) {
            #pragma unroll
            for (int j = 0; j < 8; ++j) reds[wv][j] = zs[j];
          }
          __syncthreads();
          if (tid < 8) {
            float S = 0.f;
            #pragma unroll
            for (int w = 0; w < 16; ++w) S += reds[w][tid];
            vbc[tid] = S;
          }
          __syncthreads();
          #pragma unroll
          for (int j = 0; j < 8; ++j) vbar[j] = -vbc[j];
        }
      }
      #pragma unroll
      for (int j = 0; j < 8; ++j) Know[j] -= F_LR * Kbar[j];
    }
    // ---- P = exp(K+u+v) -> LDS (and global on last iter) ----
    #pragma unroll
    for (int j = 0; j < 8; ++j) {
      float P = expf(Know[j] + u + v[j]);
      as_[j][tid] = P;
      if (it == 2) out_attn[((size_t)b * 8 + j) * NN + tid] = P;
    }
    __syncthreads();

    // ================= phase C: updates =================
    {
      float acc[8];
      #pragma unroll
      for (int j = 0; j < 8; ++j) acc[j] = 0.f;
      const float* xc = xg + ((size_t)b * NN + wv * 64) * ND + ln;
      #pragma unroll 2
      for (int i0 = 0; i0 < 64; i0 += 4) {
        float x0 = xc[(size_t)(i0 + 0) * 64];
        float x1 = xc[(size_t)(i0 + 1) * 64];
        float x2 = xc[(size_t)(i0 + 2) * 64];
        float x3 = xc[(size_t)(i0 + 3) * 64];
        int ir = wv * 64 + i0;
        #pragma unroll
        for (int j = 0; j < 8; ++j) {
          float4 a = *(const float4*)&as_[j][ir];
          acc[j] += a.x * x0 + a.y * x1 + a.z * x2 + a.w * x3;
        }
      }
      #pragma unroll
      for (int j = 0; j < 8; ++j) U.part[wv][j][ln] = acc[j];
    }
    if (it == 2 && wv < 8) {   // slot_pos from final attn
      float px = 0.f, py = 0.f;
      #pragma unroll
      for (int k = 0; k < 16; ++k) {
        int i = ln + k * 64;
        float a = as_[wv][i];
        px += a * (float)(i & 31);
        py += a * (float)(i >> 5);
      }
      #pragma unroll
      for (int m = 32; m >= 1; m >>= 1) { px += __shfl_xor(px, m, 64); py += __shfl_xor(py, m, 64); }
      if (ln == 0) {
        out_pos[(b * 8 + wv) * 2 + 0] = px * (1.f / 31.f);
        out_pos[(b * 8 + wv) * 2 + 1] = py * (1.f / 31.f);
      }
    }
    __syncthreads();
    if (wv < 8) {
      float s = 0.f;
      #pragma unroll
      for (int w = 0; w < 16; ++w) s += U.part[w][wv][ln];
      updl[wv][ln] = s;
    }
    __syncthreads();
    float updv = 0.f;
    if (wv < 8) {
      const float4* w4 = (const float4*)(Wv + ln * 64);
      const float4* u4 = (const float4*)updl[wv];
      #pragma unroll
      for (int c = 0; c < 16; ++c) {
        float4 uv = u4[c], wvv = w4[c];
        updv += uv.x * wvv.x + uv.y * wvv.y + uv.z * wvv.z + uv.w * wvv.w;
      }
      sn[wv][ln] = updv;   // reuse sn as the 'updates' row for GRU dots
    }
    __syncthreads();

    // ================= phase D: GRU + FF =================
    float hn = 0.f;
    if (wv < 8) {
      float h = slot_lds[wv][ln];
      float gi0 = bih[ln], gi1 = bih[64 + ln], gi2 = bih[128 + ln];
      float gh0 = bhh[ln], gh1 = bhh[64 + ln], gh2 = bhh[128 + ln];
      const float4* x4 = (const float4*)sn[wv];
      const float4* h4 = (const float4*)slot_lds[wv];
      const float4* wi0 = (const float4*)(wih + (size_t)ln * 64);
      const float4* wi1 = (const float4*)(wih + (size_t)(64 + ln) * 64);
      const float4* wi2 = (const float4*)(wih + (size_t)(128 + ln) * 64);
      const float4* wh0 = (const float4*)(whh + (size_t)ln * 64);
      const float4* wh1 = (const float4*)(whh + (size_t)(64 + ln) * 64);
      const float4* wh2 = (const float4*)(whh + (size_t)(128 + ln) * 64);
      #pragma unroll 4
      for (int c = 0; c < 16; ++c) {
        float4 xv = x4[c], hv = h4[c], a;
        a = wi0[c]; gi0 += xv.x * a.x + xv.y * a.y + xv.z * a.z + xv.w * a.w;
        a = wi1[c]; gi1 += xv.x * a.x + xv.y * a.y + xv.z * a.z + xv.w * a.w;
        a = wi2[c]; gi2 += xv.x * a.x + xv.y * a.y + xv.z * a.z + xv.w * a.w;
        a = wh0[c]; gh0 += hv.x * a.x + hv.y * a.y + hv.z * a.z + hv.w * a.w;
        a = wh1[c]; gh1 += hv.x * a.x + hv.y * a.y + hv.z * a.z + hv.w * a.w;
        a = wh2[c]; gh2 += hv.x * a.x + hv.y * a.y + hv.z * a.z + hv.w * a.w;
      }
      float r = 1.f / (1.f + expf(-(gi0 + gh0)));
      float z = 1.f / (1.f + expf(-(gi1 + gh1)));
      float n = tanhf(gi2 + r * gh2);
      hn = (1.f - z) * n + z * h;
      float s1 = hn, s2 = hn * hn;
      #pragma unroll
      for (int m = 32; m >= 1; m >>= 1) { s1 += __shfl_xor(s1, m, 64); s2 += __shfl_xor(s2, m, 64); }
      float mean = s1 * (1.f / 64.f);
      float var  = s2 * (1.f / 64.f) - mean * mean;
      ys[wv][ln] = (hn - mean) * rsqrtf(var + 1e-5f) * lnf_g[ln] + lnf_b[ln];
    }
    __syncthreads();
    if (wv < 8) {
      float a0 = fc1b[ln], a1 = fc1b[64 + ln];
      const float4* y4 = (const float4*)ys[wv];
      const float4* f0 = (const float4*)(fc1w + (size_t)ln * 64);
      const float4* f1 = (const float4*)(fc1w + (size_t)(64 + ln) * 64);
      #pragma unroll 4
      for (int c = 0; c < 16; ++c) {
        float4 yv = y4[c], a = f0[c], bb = f1[c];
        a0 += yv.x * a.x + yv.y * a.y + yv.z * a.z + yv.w * a.w;
        a1 += yv.x * bb.x + yv.y * bb.y + yv.z * bb.z + yv.w * bb.w;
      }
      rs[wv][ln] = fmaxf(a0, 0.f);
      rs[wv][64 + ln] = fmaxf(a1, 0.f);
    }
    __syncthreads();
    if (wv < 8) {
      float o = fc2b[ln];
      const float4* r4 = (const float4*)rs[wv];
      const float4* f2 = (const float4*)(fc2w + (size_t)ln * 128);
      #pragma unroll 4
      for (int c = 0; c < 32; ++c) {
        float4 rv = r4[c], a = f2[c];
        o += rv.x * a.x + rv.y * a.y + rv.z * a.z + rv.w * a.w;
      }
      slot_lds[wv][ln] = hn + o;
    }
    __syncthreads();
  }
  if (tid < 512) out_slots[(size_t)b * 512 + tid] = slot_lds[tid >> 6][ln];
}

// ---------------------------------------------------------------- launch
extern "C" void kernel_launch(void* const* d_in, const int* in_sizes, int n_in,
                              void* d_out, int out_size, void* d_ws, size_t ws_size,
                              hipStream_t stream) {
  const float* inputs = (const float*)d_in[0];
  const float* noise  = (const float*)d_in[1];
  const float* mu     = (const float*)d_in[2];
  const float* sigma  = (const float*)d_in[3];
  const float* Wq     = (const float*)d_in[4];
  const float* Wk     = (const float*)d_in[5];
  const float* Wv     = (const float*)d_in[6];
  const float* gwih   = (const float*)d_in[7];
  const float* gwhh   = (const float*)d_in[8];
  const float* gbih   = (const float*)d_in[9];
  const float* gbhh   = (const float*)d_in[10];
  const float* fc1w   = (const float*)d_in[11];
  const float* fc1b   = (const float*)d_in[12];
  const float* fc2w   = (const float*)d_in[13];
  const float* fc2b   = (const float*)d_in[14];
  const float* lnin_g = (const float*)d_in[15];
  const float* lnin_b = (const float*)d_in[16];
  const float* lns_g  = (const float*)d_in[17];
  const float* lns_b  = (const float*)d_in[18];
  const float* lnf_g  = (const float*)d_in[19];
  const float* lnf_b  = (const float*)d_in[20];
  const float* wi_w   = (const float*)d_in[21];
  const float* wi_b   = (const float*)d_in[22];
  const float* ws_w   = (const float*)d_in[23];
  const float* ws_b   = (const float*)d_in[24];

  float* out       = (float*)d_out;
  float* out_slots = out;                       // 256*8*64
  float* out_pos   = out + NB * NSL * ND;       // 256*8*2
  float* out_attn  = out_pos + NB * NSL * 2;    // 256*8*1024

  float* p = (float*)d_ws;
  float* xbuf  = p; p += (size_t)NB * NN * ND;  // 64 MB
  float* kkbuf = p; p += (size_t)NB * NN;
  float* wilog = p; p += (size_t)NB * NN;

  k_pre<<<(NB * NN) / 4, 256, 0, stream>>>(inputs, Wk, lnin_g, lnin_b, wi_w, wi_b,
                                           xbuf, kkbuf, wilog);
  k_mega<<<NB, 1024, 0, stream>>>(noise, mu, sigma, xbuf, kkbuf, wilog,
                                  Wq, Wk, Wv, gwih, gwhh, gbih, gbhh,
                                  fc1w, fc1b, fc2w, fc2b,
                                  lns_g, lns_b, lnf_g, lnf_b, ws_w, ws_b,
                                  out_slots, out_pos, out_attn);
}

// Round 4
// 2141.734 us; speedup vs baseline: 1.0195x; 1.0195x over previous
//
#include <hip/hip_runtime.h>
#include <math.h>

#define NB   256
#define NN   1024
#define ND   64
#define NSL  8
#define NHID 128
#define N_SINK 8
#define N_MESH 4
#define F_LR  3.0f
#define F_EPS 1e-8f

// ---------------------------------------------------------------- k_pre
// x = LN(inputs)*g+b ; kk = |x@Wk^T|^2 ; wilog = x . wi_w + wi_b
__global__ __launch_bounds__(256) void k_pre(
    const float* __restrict__ inp, const float* __restrict__ Wk,
    const float* __restrict__ lng, const float* __restrict__ lnb,
    const float* __restrict__ wiw, const float* __restrict__ wib,
    float* __restrict__ xout, float* __restrict__ kkout, float* __restrict__ wilog) {
  __shared__ __align__(16) float xs[4][64];
  int wv = threadIdx.x >> 6, ln = threadIdx.x & 63;
  size_t row = (size_t)blockIdx.x * 4 + wv;        // < 262144
  float xi = inp[row * 64 + ln];
  float s1 = xi, s2 = xi * xi;
  #pragma unroll
  for (int m = 32; m >= 1; m >>= 1) { s1 += __shfl_xor(s1, m, 64); s2 += __shfl_xor(s2, m, 64); }
  float mean = s1 * (1.f / 64.f);
  float var  = s2 * (1.f / 64.f) - mean * mean;
  float xn = (xi - mean) * rsqrtf(var + 1e-5f) * lng[ln] + lnb[ln];
  xs[wv][ln] = xn;
  xout[row * 64 + ln] = xn;
  float wl = xn * wiw[ln];
  #pragma unroll
  for (int m = 32; m >= 1; m >>= 1) wl += __shfl_xor(wl, m, 64);
  __syncthreads();
  const float4* w4 = (const float4*)(Wk + ln * 64);
  const float4* x4 = (const float4*)xs[wv];
  float ko = 0.f;
  #pragma unroll
  for (int c = 0; c < 16; ++c) {
    float4 a = w4[c], xv = x4[c];
    ko += a.x * xv.x + a.y * xv.y + a.z * xv.z + a.w * xv.w;
  }
  float kk = ko * ko;
  #pragma unroll
  for (int m = 32; m >= 1; m >>= 1) kk += __shfl_xor(kk, m, 64);
  if (ln == 0) { kkout[row] = kk; wilog[row] = wl + wib[0]; }
}

// ---------------------------------------------------------------- helpers
__device__ __forceinline__ void wave_max8(float* a) {
  #pragma unroll
  for (int m = 32; m >= 1; m >>= 1) {
    #pragma unroll
    for (int j = 0; j < 8; ++j) a[j] = fmaxf(a[j], __shfl_xor(a[j], m, 64));
  }
}
__device__ __forceinline__ void wave_sum8(float* a) {
  #pragma unroll
  for (int m = 32; m >= 1; m >>= 1) {
    #pragma unroll
    for (int j = 0; j < 8; ++j) a[j] += __shfl_xor(a[j], m, 64);
  }
}

// ---------------------------------------------------------------- k_mega
// One block per batch; 1024 threads = 16 waves = 4 waves/EU -> pin register
// budget at 4 waves/EU (128 VGPR) so the Sinkhorn state never spills.
// Wave-uniform 8-vectors (v, lb, vbar) live in LDS broadcast slots, not VGPRs.
__global__ __launch_bounds__(1024)
__attribute__((amdgpu_waves_per_eu(4, 4)))
void k_mega(
    const float* __restrict__ noise, const float* __restrict__ mu,
    const float* __restrict__ sigma,
    const float* __restrict__ xg, const float* __restrict__ kkg,
    const float* __restrict__ wilogg,
    const float* __restrict__ Wq, const float* __restrict__ Wk,
    const float* __restrict__ Wv,
    const float* __restrict__ wih, const float* __restrict__ whh,
    const float* __restrict__ bih, const float* __restrict__ bhh,
    const float* __restrict__ fc1w, const float* __restrict__ fc1b,
    const float* __restrict__ fc2w, const float* __restrict__ fc2b,
    const float* __restrict__ lns_g, const float* __restrict__ lns_b,
    const float* __restrict__ lnf_g, const float* __restrict__ lnf_b,
    const float* __restrict__ wsw, const float* __restrict__ wsb,
    float* __restrict__ out_slots, float* __restrict__ out_pos,
    float* __restrict__ out_attn) {
  __shared__ __align__(16) float slot_lds[8][64];
  __shared__ __align__(16) float sn[8][64];      // slot LN result; later: updates row
  __shared__ __align__(16) float qsh[8][64];
  __shared__ __align__(16) float qs[8][64];
  __shared__ __align__(16) float updl[8][64];
  __shared__ __align__(16) float ys[8][64];
  __shared__ __align__(16) float rs[8][128];
  __shared__ __align__(16) union {
    float uhist[N_SINK][NN];    // phase B
    float part[16][8][64];      // phase C
  } U;
  __shared__ __align__(16) float as_[8][NN];     // attn (transposed), 32 KB
  __shared__ float redm[16][8], reds[16][8];
  __shared__ float vbc[8];                       // current v (broadcast)
  __shared__ float vbarbc[8];                    // current vbar (broadcast)
  __shared__ float vhist[N_SINK][8];
  __shared__ float bmv[8], q2s[8], lbs[8];
  __shared__ float redf[16], bcf[1];

  int b = blockIdx.x, tid = threadIdx.x;
  int wv = tid >> 6, ln = tid & 63;

  // ---- slots init ----
  if (tid < 512) {
    slot_lds[tid >> 6][ln] = mu[ln] + (fabsf(sigma[ln]) + F_EPS) * noise[(size_t)b * 512 + tid];
  }
  // ---- la = log(8*softmax(wilog)+eps), block-wide ----
  float wl = wilogg[(size_t)b * NN + tid];
  float m0 = wl;
  #pragma unroll
  for (int s = 32; s >= 1; s >>= 1) m0 = fmaxf(m0, __shfl_xor(m0, s, 64));
  if (ln == 0) redf[wv] = m0;
  __syncthreads();
  if (tid == 0) { float a = redf[0]; for (int w = 1; w < 16; ++w) a = fmaxf(a, redf[w]); bcf[0] = a; }
  __syncthreads();
  m0 = bcf[0];
  float e0 = expf(wl - m0), se0 = e0;
  #pragma unroll
  for (int s = 32; s >= 1; s >>= 1) se0 += __shfl_xor(se0, s, 64);
  __syncthreads();
  if (ln == 0) redf[wv] = se0;
  __syncthreads();
  if (tid == 0) { float a = 0.f; for (int w = 0; w < 16; ++w) a += redf[w]; bcf[0] = a; }
  __syncthreads();
  float la = logf(8.f * e0 / bcf[0] + F_EPS);
  float kk = kkg[(size_t)b * NN + tid];
  const float4* xrow4 = (const float4*)(xg + ((size_t)b * NN + tid) * ND);

  float u = 0.f;

  for (int it = 0; it < 3; ++it) {
    // ================= phase A: slotpre =================
    if (wv < 8) {
      float x = slot_lds[wv][ln];
      float s1 = x, s2 = x * x;
      #pragma unroll
      for (int m = 32; m >= 1; m >>= 1) { s1 += __shfl_xor(s1, m, 64); s2 += __shfl_xor(s2, m, 64); }
      float mean = s1 * (1.f / 64.f);
      float var  = s2 * (1.f / 64.f) - mean * mean;
      float xn = (x - mean) * rsqrtf(var + 1e-5f) * lns_g[ln] + lns_b[ln];
      sn[wv][ln] = xn;
      float wlg = xn * wsw[ln];
      #pragma unroll
      for (int m = 32; m >= 1; m >>= 1) wlg += __shfl_xor(wlg, m, 64);
      if (ln == 0) bmv[wv] = wlg + wsb[0];
    }
    __syncthreads();
    if (wv < 8) {
      const float4* w4 = (const float4*)(Wq + ln * 64);
      const float4* x4 = (const float4*)sn[wv];
      float q = 0.f;
      #pragma unroll
      for (int c = 0; c < 16; ++c) {
        float4 a = w4[c], xv = x4[c];
        q += a.x * xv.x + a.y * xv.y + a.z * xv.z + a.w * xv.w;
      }
      qsh[wv][ln] = q;
      float q2 = q * q;
      #pragma unroll
      for (int m = 32; m >= 1; m >>= 1) q2 += __shfl_xor(q2, m, 64);
      if (ln == 0) q2s[wv] = q2;
    }
    if (tid >= 512 && tid < 520) {   // lbs from bmv (ready after prev barrier)
      int j = tid - 512;
      float mx = bmv[0];
      #pragma unroll
      for (int jj = 1; jj < 8; ++jj) mx = fmaxf(mx, bmv[jj]);
      float ss = 0.f;
      #pragma unroll
      for (int jj = 0; jj < 8; ++jj) ss += expf(bmv[jj] - mx);
      lbs[j] = logf(8.f * expf(bmv[j] - mx) / ss + F_EPS);
    }
    __syncthreads();
    if (wv < 8) {
      float qt = 0.f;
      for (int o = 0; o < 64; ++o) qt = fmaf(qsh[wv][o], Wk[o * 64 + ln], qt);
      qs[wv][ln] = qt;
    }
    __syncthreads();

    // ================= phase B: MESH + sinkhorn =================
    float Know[8];
    {
      float dot[8];
      #pragma unroll
      for (int j = 0; j < 8; ++j) dot[j] = 0.f;
      #pragma unroll 4
      for (int c = 0; c < 16; ++c) {
        float4 xv = xrow4[c];
        #pragma unroll
        for (int j = 0; j < 8; ++j) {
          const float4 qv = *(const float4*)&qs[j][c * 4];
          dot[j] += xv.x * qv.x + xv.y * qv.y + xv.z * qv.z + xv.w * qv.w;
        }
      }
      #pragma unroll
      for (int j = 0; j < 8; ++j) {
        float d2 = kk + q2s[j] - 2.f * dot[j];
        Know[j] = -sqrtf(fmaxf(d2, 1e-12f));
      }
    }
    for (int phase = 0; phase <= N_MESH; ++phase) {
      bool cold = (phase < N_MESH);
      // ---- forward: 8 sinkhorn iterations ----
      for (int t = 0; t < N_SINK; ++t) {
        bool z0 = cold && (t == 0);
        // u-step (row LSE, thread-local); v read from LDS broadcast
        float mx = -3.4e38f;
        #pragma unroll
        for (int j = 0; j < 8; ++j) {
          float vj = z0 ? 0.f : vbc[j];
          mx = fmaxf(mx, Know[j] + vj);
        }
        float se = 0.f;
        #pragma unroll
        for (int j = 0; j < 8; ++j) {
          float vj = z0 ? 0.f : vbc[j];
          se += expf(Know[j] + vj - mx);
        }
        u = la - (mx + logf(se));
        U.uhist[t][tid] = u;
        // v-step: fused col-LSE (per-wave LSE, cross-wave merge)
        float mm[8], pp[8];
        #pragma unroll
        for (int j = 0; j < 8; ++j) mm[j] = Know[j] + u;
        wave_max8(mm);
        #pragma unroll
        for (int j = 0; j < 8; ++j) pp[j] = expf(Know[j] + u - mm[j]);
        wave_sum8(pp);
        if (ln == 0) {
          #pragma unroll
          for (int j = 0; j < 8; ++j) { redm[wv][j] = mm[j]; reds[wv][j] = pp[j]; }
        }
        __syncthreads();
        if (tid < 8) {
          float M = redm[0][tid];
          #pragma unroll
          for (int w = 1; w < 16; ++w) M = fmaxf(M, redm[w][tid]);
          float S = 0.f;
          #pragma unroll
          for (int w = 0; w < 16; ++w) S += reds[w][tid] * expf(redm[w][tid] - M);
          float vj = lbs[tid] - (M + logf(S));
          vbc[tid] = vj; vhist[t][tid] = vj;
        }
        __syncthreads();
      }
      if (phase == N_MESH) break;

      // ---- backward: dH/dK ----
      float Kbar[8], ubarT;
      {
        float cs[8], gsum = 0.f;
        #pragma unroll
        for (int j = 0; j < 8; ++j) {
          float P  = expf(Know[j] + u + vbc[j]);
          float pe = P + F_EPS;
          float G  = -(logf(pe) + P / pe);
          float gp = G * P;
          Kbar[j] = gp; cs[j] = gp; gsum += gp;
        }
        ubarT = gsum;
        wave_sum8(cs);
        if (ln == 0) {
          #pragma unroll
          for (int j = 0; j < 8; ++j) reds[wv][j] = cs[j];
        }
        __syncthreads();
        if (tid < 8) {
          float S = 0.f;
          #pragma unroll
          for (int w = 0; w < 16; ++w) S += reds[w][tid];
          vbarbc[tid] = S;
        }
        __syncthreads();
      }
      for (int t = N_SINK - 1; t >= 0; --t) {
        float ut = U.uhist[t][tid];
        float dsum = (t == N_SINK - 1) ? ubarT : 0.f;
        #pragma unroll
        for (int j = 0; j < 8; ++j) {
          float w  = expf(Know[j] + ut + vhist[t][j] - lbs[j]);
          float vw = vbarbc[j] * w;
          Kbar[j] -= vw; dsum -= vw;
        }
        float zs[8];
        #pragma unroll
        for (int j = 0; j < 8; ++j) {
          float vprev = (t > 0) ? vhist[t - 1][j] : 0.f;
          float z  = expf(Know[j] + vprev + ut - la);
          float uz = dsum * z;
          Kbar[j] -= uz; zs[j] = uz;
        }
        if (t > 0) {
          wave_sum8(zs);
          if (ln == 0) {
            #pragma unroll
            for (int j = 0; j < 8; ++j) reds[wv][j] = zs[j];
          }
          __syncthreads();
          if (tid < 8) {
            float S = 0.f;
            #pragma unroll
            for (int w = 0; w < 16; ++w) S += reds[w][tid];
            vbarbc[tid] = -S;
          }
          __syncthreads();
        }
      }
      #pragma unroll
      for (int j = 0; j < 8; ++j) Know[j] -= F_LR * Kbar[j];
    }
    // ---- P = exp(K+u+v) -> LDS (and global on last iter) ----
    #pragma unroll
    for (int j = 0; j < 8; ++j) {
      float P = expf(Know[j] + u + vbc[j]);
      as_[j][tid] = P;
      if (it == 2) out_attn[((size_t)b * 8 + j) * NN + tid] = P;
    }
    __syncthreads();

    // ================= phase C: updates =================
    {
      float acc[8];
      #pragma unroll
      for (int j = 0; j < 8; ++j) acc[j] = 0.f;
      const float* xc = xg + ((size_t)b * NN + wv * 64) * ND + ln;
      #pragma unroll 2
      for (int i0 = 0; i0 < 64; i0 += 4) {
        float x0 = xc[(size_t)(i0 + 0) * 64];
        float x1 = xc[(size_t)(i0 + 1) * 64];
        float x2 = xc[(size_t)(i0 + 2) * 64];
        float x3 = xc[(size_t)(i0 + 3) * 64];
        int ir = wv * 64 + i0;
        #pragma unroll
        for (int j = 0; j < 8; ++j) {
          float4 a = *(const float4*)&as_[j][ir];
          acc[j] += a.x * x0 + a.y * x1 + a.z * x2 + a.w * x3;
        }
      }
      #pragma unroll
      for (int j = 0; j < 8; ++j) U.part[wv][j][ln] = acc[j];
    }
    if (it == 2 && wv < 8) {   // slot_pos from final attn
      float px = 0.f, py = 0.f;
      #pragma unroll
      for (int k = 0; k < 16; ++k) {
        int i = ln + k * 64;
        float a = as_[wv][i];
        px += a * (float)(i & 31);
        py += a * (float)(i >> 5);
      }
      #pragma unroll
      for (int m = 32; m >= 1; m >>= 1) { px += __shfl_xor(px, m, 64); py += __shfl_xor(py, m, 64); }
      if (ln == 0) {
        out_pos[(b * 8 + wv) * 2 + 0] = px * (1.f / 31.f);
        out_pos[(b * 8 + wv) * 2 + 1] = py * (1.f / 31.f);
      }
    }
    __syncthreads();
    if (wv < 8) {
      float s = 0.f;
      #pragma unroll
      for (int w = 0; w < 16; ++w) s += U.part[w][wv][ln];
      updl[wv][ln] = s;
    }
    __syncthreads();
    if (wv < 8) {
      const float4* w4 = (const float4*)(Wv + ln * 64);
      const float4* u4 = (const float4*)updl[wv];
      float updv = 0.f;
      #pragma unroll
      for (int c = 0; c < 16; ++c) {
        float4 uv = u4[c], wvv = w4[c];
        updv += uv.x * wvv.x + uv.y * wvv.y + uv.z * wvv.z + uv.w * wvv.w;
      }
      sn[wv][ln] = updv;   // reuse sn as the 'updates' row for GRU dots
    }
    __syncthreads();

    // ================= phase D: GRU + FF =================
    float hn = 0.f;
    if (wv < 8) {
      float h = slot_lds[wv][ln];
      float gi0 = bih[ln], gi1 = bih[64 + ln], gi2 = bih[128 + ln];
      float gh0 = bhh[ln], gh1 = bhh[64 + ln], gh2 = bhh[128 + ln];
      const float4* x4 = (const float4*)sn[wv];
      const float4* h4 = (const float4*)slot_lds[wv];
      const float4* wi0 = (const float4*)(wih + (size_t)ln * 64);
      const float4* wi1 = (const float4*)(wih + (size_t)(64 + ln) * 64);
      const float4* wi2 = (const float4*)(wih + (size_t)(128 + ln) * 64);
      const float4* wh0 = (const float4*)(whh + (size_t)ln * 64);
      const float4* wh1 = (const float4*)(whh + (size_t)(64 + ln) * 64);
      const float4* wh2 = (const float4*)(whh + (size_t)(128 + ln) * 64);
      #pragma unroll 4
      for (int c = 0; c < 16; ++c) {
        float4 xv = x4[c], hv = h4[c], a;
        a = wi0[c]; gi0 += xv.x * a.x + xv.y * a.y + xv.z * a.z + xv.w * a.w;
        a = wi1[c]; gi1 += xv.x * a.x + xv.y * a.y + xv.z * a.z + xv.w * a.w;
        a = wi2[c]; gi2 += xv.x * a.x + xv.y * a.y + xv.z * a.z + xv.w * a.w;
        a = wh0[c]; gh0 += hv.x * a.x + hv.y * a.y + hv.z * a.z + hv.w * a.w;
        a = wh1[c]; gh1 += hv.x * a.x + hv.y * a.y + hv.z * a.z + hv.w * a.w;
        a = wh2[c]; gh2 += hv.x * a.x + hv.y * a.y + hv.z * a.z + hv.w * a.w;
      }
      float r = 1.f / (1.f + expf(-(gi0 + gh0)));
      float z = 1.f / (1.f + expf(-(gi1 + gh1)));
      float n = tanhf(gi2 + r * gh2);
      hn = (1.f - z) * n + z * h;
      float s1 = hn, s2 = hn * hn;
      #pragma unroll
      for (int m = 32; m >= 1; m >>= 1) { s1 += __shfl_xor(s1, m, 64); s2 += __shfl_xor(s2, m, 64); }
      float mean = s1 * (1.f / 64.f);
      float var  = s2 * (1.f / 64.f) - mean * mean;
      ys[wv][ln] = (hn - mean) * rsqrtf(var + 1e-5f) * lnf_g[ln] + lnf_b[ln];
    }
    __syncthreads();
    if (wv < 8) {
      float a0 = fc1b[ln], a1 = fc1b[64 + ln];
      const float4* y4 = (const float4*)ys[wv];
      const float4* f0 = (const float4*)(fc1w + (size_t)ln * 64);
      const float4* f1 = (const float4*)(fc1w + (size_t)(64 + ln) * 64);
      #pragma unroll 4
      for (int c = 0; c < 16; ++c) {
        float4 yv = y4[c], a = f0[c], bb = f1[c];
        a0 += yv.x * a.x + yv.y * a.y + yv.z * a.z + yv.w * a.w;
        a1 += yv.x * bb.x + yv.y * bb.y + yv.z * bb.z + yv.w * bb.w;
      }
      rs[wv][ln] = fmaxf(a0, 0.f);
      rs[wv][64 + ln] = fmaxf(a1, 0.f);
    }
    __syncthreads();
    if (wv < 8) {
      float o = fc2b[ln];
      const float4* r4 = (const float4*)rs[wv];
      const float4* f2 = (const float4*)(fc2w + (size_t)ln * 128);
      #pragma unroll 4
      for (int c = 0; c < 32; ++c) {
        float4 rv = r4[c], a = f2[c];
        o += rv.x * a.x + rv.y * a.y + rv.z * a.z + rv.w * a.w;
      }
      slot_lds[wv][ln] = hn + o;
    }
    __syncthreads();
  }
  if (tid < 512) out_slots[(size_t)b * 512 + tid] = slot_lds[tid >> 6][ln];
}

// ---------------------------------------------------------------- launch
extern "C" void kernel_launch(void* const* d_in, const int* in_sizes, int n_in,
                              void* d_out, int out_size, void* d_ws, size_t ws_size,
                              hipStream_t stream) {
  const float* inputs = (const float*)d_in[0];
  const float* noise  = (const float*)d_in[1];
  const float* mu     = (const float*)d_in[2];
  const float* sigma  = (const float*)d_in[3];
  const float* Wq     = (const float*)d_in[4];
  const float* Wk     = (const float*)d_in[5];
  const float* Wv     = (const float*)d_in[6];
  const float* gwih   = (const float*)d_in[7];
  const float* gwhh   = (const float*)d_in[8];
  const float* gbih   = (const float*)d_in[9];
  const float* gbhh   = (const float*)d_in[10];
  const float* fc1w   = (const float*)d_in[11];
  const float* fc1b   = (const float*)d_in[12];
  const float* fc2w   = (const float*)d_in[13];
  const float* fc2b   = (const float*)d_in[14];
  const float* lnin_g = (const float*)d_in[15];
  const float* lnin_b = (const float*)d_in[16];
  const float* lns_g  = (const float*)d_in[17];
  const float* lns_b  = (const float*)d_in[18];
  const float* lnf_g  = (const float*)d_in[19];
  const float* lnf_b  = (const float*)d_in[20];
  const float* wi_w   = (const float*)d_in[21];
  const float* wi_b   = (const float*)d_in[22];
  const float* ws_w   = (const float*)d_in[23];
  const float* ws_b   = (const float*)d_in[24];

  float* out       = (float*)d_out;
  float* out_slots = out;                       // 256*8*64
  float* out_pos   = out + NB * NSL * ND;       // 256*8*2
  float* out_attn  = out_pos + NB * NSL * 2;    // 256*8*1024

  float* p = (float*)d_ws;
  float* xbuf  = p; p += (size_t)NB * NN * ND;  // 64 MB
  float* kkbuf = p; p += (size_t)NB * NN;
  float* wilog = p; p += (size_t)NB * NN;

  k_pre<<<(NB * NN) / 4, 256, 0, stream>>>(inputs, Wk, lnin_g, lnin_b, wi_w, wi_b,
                                           xbuf, kkbuf, wilog);
  k_mega<<<NB, 1024, 0, stream>>>(noise, mu, sigma, xbuf, kkbuf, wilog,
                                  Wq, Wk, Wv, gwih, gwhh, gbih, gbhh,
                                  fc1w, fc1b, fc2w, fc2b,
                                  lns_g, lns_b, lnf_g, lnf_b, ws_w, ws_b,
                                  out_slots, out_pos, out_attn);
}

// Round 5
// 1329.971 us; speedup vs baseline: 1.6418x; 1.6104x over previous
//
#include <hip/hip_runtime.h>
#include <math.h>

#define NB   256
#define NN   1024
#define ND   64
#define NSL  8
#define NHID 128
#define N_SINK 8
#define N_MESH 4
#define F_LR  3.0f
#define F_EPS 1e-8f

// ---------------------------------------------------------------- k_pre
// x = LN(inputs)*g+b ; kk = |x@Wk^T|^2 ; wilog = x . wi_w + wi_b
__global__ __launch_bounds__(256) void k_pre(
    const float* __restrict__ inp, const float* __restrict__ Wk,
    const float* __restrict__ lng, const float* __restrict__ lnb,
    const float* __restrict__ wiw, const float* __restrict__ wib,
    float* __restrict__ xout, float* __restrict__ kkout, float* __restrict__ wilog) {
  __shared__ __align__(16) float xs[4][64];
  int wv = threadIdx.x >> 6, ln = threadIdx.x & 63;
  size_t row = (size_t)blockIdx.x * 4 + wv;        // < 262144
  float xi = inp[row * 64 + ln];
  float s1 = xi, s2 = xi * xi;
  #pragma unroll
  for (int m = 32; m >= 1; m >>= 1) { s1 += __shfl_xor(s1, m, 64); s2 += __shfl_xor(s2, m, 64); }
  float mean = s1 * (1.f / 64.f);
  float var  = s2 * (1.f / 64.f) - mean * mean;
  float xn = (xi - mean) * rsqrtf(var + 1e-5f) * lng[ln] + lnb[ln];
  xs[wv][ln] = xn;
  xout[row * 64 + ln] = xn;
  float wl = xn * wiw[ln];
  #pragma unroll
  for (int m = 32; m >= 1; m >>= 1) wl += __shfl_xor(wl, m, 64);
  __syncthreads();
  const float4* w4 = (const float4*)(Wk + ln * 64);
  const float4* x4 = (const float4*)xs[wv];
  float ko = 0.f;
  #pragma unroll
  for (int c = 0; c < 16; ++c) {
    float4 a = w4[c], xv = x4[c];
    ko += a.x * xv.x + a.y * xv.y + a.z * xv.z + a.w * xv.w;
  }
  float kk = ko * ko;
  #pragma unroll
  for (int m = 32; m >= 1; m >>= 1) kk += __shfl_xor(kk, m, 64);
  if (ln == 0) { kkout[row] = kk; wilog[row] = wl + wib[0]; }
}

// ---------------------------------------------------------------- k_mega
// One block per batch. Column reductions go through an LDS transpose
// (cols[8][1024]) so per-thread register state stays well under the 64-VGPR
// budget the allocator insists on for 1024-thread blocks (rounds 2-4 showed
// 0.4-1.6 GB/dispatch of spill traffic with the butterfly scheme).
__global__ __launch_bounds__(1024, 4) void k_mega(
    const float* __restrict__ noise, const float* __restrict__ mu,
    const float* __restrict__ sigma,
    const float* __restrict__ xg, const float* __restrict__ kkg,
    const float* __restrict__ wilogg,
    const float* __restrict__ Wq, const float* __restrict__ Wk,
    const float* __restrict__ Wv,
    const float* __restrict__ wih, const float* __restrict__ whh,
    const float* __restrict__ bih, const float* __restrict__ bhh,
    const float* __restrict__ fc1w, const float* __restrict__ fc1b,
    const float* __restrict__ fc2w, const float* __restrict__ fc2b,
    const float* __restrict__ lns_g, const float* __restrict__ lns_b,
    const float* __restrict__ lnf_g, const float* __restrict__ lnf_b,
    const float* __restrict__ wsw, const float* __restrict__ wsb,
    float* __restrict__ out_slots, float* __restrict__ out_pos,
    float* __restrict__ out_attn) {
  __shared__ __align__(16) float slot_lds[8][64];
  __shared__ __align__(16) float sn[8][64];      // slot LN result; later: updates row
  __shared__ __align__(16) float qsh[8][64];
  __shared__ __align__(16) float qs[8][64];
  __shared__ __align__(16) float updl[8][64];
  __shared__ __align__(16) float ys[8][64];
  __shared__ __align__(16) float rs[8][128];
  __shared__ __align__(16) union {
    float uhist[N_SINK][NN];    // phase B
    float part[16][8][64];      // phase C
  } U;
  __shared__ __align__(16) float cols[8][NN];    // col-reduce scratch; then attn^T
  __shared__ float vbc[8];                       // current v (broadcast)
  __shared__ float vbarbc[8];                    // current vbar (broadcast)
  __shared__ float vhist[N_SINK][8];
  __shared__ float bmv[8], q2s[8], lbs[8];
  __shared__ float redf[16], bcf[1];

  int b = blockIdx.x, tid = threadIdx.x;
  int wv = tid >> 6, ln = tid & 63;

  // ---- slots init ----
  if (tid < 512) {
    slot_lds[tid >> 6][ln] = mu[ln] + (fabsf(sigma[ln]) + F_EPS) * noise[(size_t)b * 512 + tid];
  }
  // ---- la = log(8*softmax(wilog)+eps), block-wide ----
  float wl = wilogg[(size_t)b * NN + tid];
  float m0 = wl;
  #pragma unroll
  for (int s = 32; s >= 1; s >>= 1) m0 = fmaxf(m0, __shfl_xor(m0, s, 64));
  if (ln == 0) redf[wv] = m0;
  __syncthreads();
  if (tid == 0) { float a = redf[0]; for (int w = 1; w < 16; ++w) a = fmaxf(a, redf[w]); bcf[0] = a; }
  __syncthreads();
  m0 = bcf[0];
  float e0 = __expf(wl - m0), se0 = e0;
  #pragma unroll
  for (int s = 32; s >= 1; s >>= 1) se0 += __shfl_xor(se0, s, 64);
  __syncthreads();
  if (ln == 0) redf[wv] = se0;
  __syncthreads();
  if (tid == 0) { float a = 0.f; for (int w = 0; w < 16; ++w) a += redf[w]; bcf[0] = a; }
  __syncthreads();
  float la = __logf(8.f * e0 / bcf[0] + F_EPS);
  float kk = kkg[(size_t)b * NN + tid];
  const float4* xrow4 = (const float4*)(xg + ((size_t)b * NN + tid) * ND);

  float u = 0.f;

  for (int it = 0; it < 3; ++it) {
    // ================= phase A: slotpre =================
    if (wv < 8) {
      float x = slot_lds[wv][ln];
      float s1 = x, s2 = x * x;
      #pragma unroll
      for (int m = 32; m >= 1; m >>= 1) { s1 += __shfl_xor(s1, m, 64); s2 += __shfl_xor(s2, m, 64); }
      float mean = s1 * (1.f / 64.f);
      float var  = s2 * (1.f / 64.f) - mean * mean;
      float xn = (x - mean) * rsqrtf(var + 1e-5f) * lns_g[ln] + lns_b[ln];
      sn[wv][ln] = xn;
      float wlg = xn * wsw[ln];
      #pragma unroll
      for (int m = 32; m >= 1; m >>= 1) wlg += __shfl_xor(wlg, m, 64);
      if (ln == 0) bmv[wv] = wlg + wsb[0];
    }
    __syncthreads();
    if (wv < 8) {
      const float4* w4 = (const float4*)(Wq + ln * 64);
      const float4* x4 = (const float4*)sn[wv];
      float q = 0.f;
      #pragma unroll
      for (int c = 0; c < 16; ++c) {
        float4 a = w4[c], xv = x4[c];
        q += a.x * xv.x + a.y * xv.y + a.z * xv.z + a.w * xv.w;
      }
      qsh[wv][ln] = q;
      float q2 = q * q;
      #pragma unroll
      for (int m = 32; m >= 1; m >>= 1) q2 += __shfl_xor(q2, m, 64);
      if (ln == 0) q2s[wv] = q2;
    }
    if (tid >= 512 && tid < 520) {   // lbs from bmv (ready after prev barrier)
      int j = tid - 512;
      float mx = bmv[0];
      #pragma unroll
      for (int jj = 1; jj < 8; ++jj) mx = fmaxf(mx, bmv[jj]);
      float ss = 0.f;
      #pragma unroll
      for (int jj = 0; jj < 8; ++jj) ss += __expf(bmv[jj] - mx);
      lbs[j] = __logf(8.f * __expf(bmv[j] - mx) / ss + F_EPS);
    }
    __syncthreads();
    if (wv < 8) {
      float qt = 0.f;
      for (int o = 0; o < 64; ++o) qt = fmaf(qsh[wv][o], Wk[o * 64 + ln], qt);
      qs[wv][ln] = qt;
    }
    __syncthreads();

    // ================= phase B: MESH + sinkhorn =================
    float Know[8];
    {
      float dot[8];
      #pragma unroll
      for (int j = 0; j < 8; ++j) dot[j] = 0.f;
      #pragma unroll 4
      for (int c = 0; c < 16; ++c) {
        float4 xv = xrow4[c];
        #pragma unroll
        for (int j = 0; j < 8; ++j) {
          const float4 qv = *(const float4*)&qs[j][c * 4];
          dot[j] += xv.x * qv.x + xv.y * qv.y + xv.z * qv.z + xv.w * qv.w;
        }
      }
      #pragma unroll
      for (int j = 0; j < 8; ++j) {
        float d2 = kk + q2s[j] - 2.f * dot[j];
        Know[j] = -sqrtf(fmaxf(d2, 1e-12f));
      }
    }
    for (int phase = 0; phase <= N_MESH; ++phase) {
      bool cold = (phase < N_MESH);
      // ---- forward: 8 sinkhorn iterations ----
      for (int t = 0; t < N_SINK; ++t) {
        bool z0 = cold && (t == 0);
        // u-step (row LSE, thread-local); v from LDS broadcast
        float c0[8];
        #pragma unroll
        for (int j = 0; j < 8; ++j) c0[j] = Know[j] + (z0 ? 0.f : vbc[j]);
        float mx = c0[0];
        #pragma unroll
        for (int j = 1; j < 8; ++j) mx = fmaxf(mx, c0[j]);
        float se = 0.f;
        #pragma unroll
        for (int j = 0; j < 8; ++j) se += __expf(c0[j] - mx);
        u = la - (mx + __logf(se));
        U.uhist[t][tid] = u;
        // v-step: transpose to LDS, waves 0-7 reduce one column each
        #pragma unroll
        for (int j = 0; j < 8; ++j) cols[j][tid] = Know[j] + u;
        __syncthreads();
        if (wv < 8) {
          const float* cp = &cols[wv][ln];
          float M = cp[0];
          #pragma unroll
          for (int k = 1; k < 16; ++k) M = fmaxf(M, cp[k * 64]);
          #pragma unroll
          for (int d = 32; d >= 1; d >>= 1) M = fmaxf(M, __shfl_xor(M, d, 64));
          float S = 0.f;
          #pragma unroll
          for (int k = 0; k < 16; ++k) S += __expf(cp[k * 64] - M);
          #pragma unroll
          for (int d = 32; d >= 1; d >>= 1) S += __shfl_xor(S, d, 64);
          if (ln == 0) {
            float vj = lbs[wv] - (M + __logf(S));
            vbc[wv] = vj; vhist[t][wv] = vj;
          }
        }
        __syncthreads();
      }
      if (phase == N_MESH) break;

      // ---- backward: dH/dK ----
      float Kbar[8], ubarT;
      {
        float gsum = 0.f;
        #pragma unroll
        for (int j = 0; j < 8; ++j) {
          float P  = __expf(Know[j] + u + vbc[j]);
          float pe = P + F_EPS;
          float G  = -(__logf(pe) + P / pe);
          float gp = G * P;
          Kbar[j] = gp; gsum += gp;
          cols[j][tid] = gp;
        }
        ubarT = gsum;
      }
      __syncthreads();
      if (wv < 8) {
        const float* cp = &cols[wv][ln];
        float S = 0.f;
        #pragma unroll
        for (int k = 0; k < 16; ++k) S += cp[k * 64];
        #pragma unroll
        for (int d = 32; d >= 1; d >>= 1) S += __shfl_xor(S, d, 64);
        if (ln == 0) vbarbc[wv] = S;
      }
      __syncthreads();
      for (int t = N_SINK - 1; t >= 0; --t) {
        float ut = U.uhist[t][tid];
        float dsum = (t == N_SINK - 1) ? ubarT : 0.f;
        #pragma unroll
        for (int j = 0; j < 8; ++j) {
          float w  = __expf(Know[j] + ut + vhist[t][j] - lbs[j]);
          float vw = vbarbc[j] * w;
          Kbar[j] -= vw; dsum -= vw;
        }
        #pragma unroll
        for (int j = 0; j < 8; ++j) {
          float vprev = (t > 0) ? vhist[t - 1][j] : 0.f;
          float z  = __expf(Know[j] + vprev + ut - la);
          float uz = dsum * z;
          Kbar[j] -= uz;
          cols[j][tid] = uz;
        }
        if (t > 0) {
          __syncthreads();
          if (wv < 8) {
            const float* cp = &cols[wv][ln];
            float S = 0.f;
            #pragma unroll
            for (int k = 0; k < 16; ++k) S += cp[k * 64];
            #pragma unroll
            for (int d = 32; d >= 1; d >>= 1) S += __shfl_xor(S, d, 64);
            if (ln == 0) vbarbc[wv] = -S;
          }
          __syncthreads();
        }
      }
      #pragma unroll
      for (int j = 0; j < 8; ++j) Know[j] -= F_LR * Kbar[j];
    }
    // ---- P = exp(K+u+v) -> cols (attn^T), global on last iter ----
    #pragma unroll
    for (int j = 0; j < 8; ++j) {
      float P = __expf(Know[j] + u + vbc[j]);
      cols[j][tid] = P;
      if (it == 2) out_attn[((size_t)b * 8 + j) * NN + tid] = P;
    }
    __syncthreads();

    // ================= phase C: updates =================
    {
      float acc[8];
      #pragma unroll
      for (int j = 0; j < 8; ++j) acc[j] = 0.f;
      const float* xc = xg + ((size_t)b * NN + wv * 64) * ND + ln;
      #pragma unroll 2
      for (int i0 = 0; i0 < 64; i0 += 4) {
        float x0 = xc[(size_t)(i0 + 0) * 64];
        float x1 = xc[(size_t)(i0 + 1) * 64];
        float x2 = xc[(size_t)(i0 + 2) * 64];
        float x3 = xc[(size_t)(i0 + 3) * 64];
        int ir = wv * 64 + i0;
        #pragma unroll
        for (int j = 0; j < 8; ++j) {
          float4 a = *(const float4*)&cols[j][ir];
          acc[j] += a.x * x0 + a.y * x1 + a.z * x2 + a.w * x3;
        }
      }
      #pragma unroll
      for (int j = 0; j < 8; ++j) U.part[wv][j][ln] = acc[j];
    }
    if (it == 2 && wv < 8) {   // slot_pos from final attn
      float px = 0.f, py = 0.f;
      #pragma unroll
      for (int k = 0; k < 16; ++k) {
        int i = ln + k * 64;
        float a = cols[wv][i];
        px += a * (float)(i & 31);
        py += a * (float)(i >> 5);
      }
      #pragma unroll
      for (int m = 32; m >= 1; m >>= 1) { px += __shfl_xor(px, m, 64); py += __shfl_xor(py, m, 64); }
      if (ln == 0) {
        out_pos[(b * 8 + wv) * 2 + 0] = px * (1.f / 31.f);
        out_pos[(b * 8 + wv) * 2 + 1] = py * (1.f / 31.f);
      }
    }
    __syncthreads();
    if (wv < 8) {
      float s = 0.f;
      #pragma unroll
      for (int w = 0; w < 16; ++w) s += U.part[w][wv][ln];
      updl[wv][ln] = s;
    }
    __syncthreads();
    if (wv < 8) {
      const float4* w4 = (const float4*)(Wv + ln * 64);
      const float4* u4 = (const float4*)updl[wv];
      float updv = 0.f;
      #pragma unroll
      for (int c = 0; c < 16; ++c) {
        float4 uv = u4[c], wvv = w4[c];
        updv += uv.x * wvv.x + uv.y * wvv.y + uv.z * wvv.z + uv.w * wvv.w;
      }
      sn[wv][ln] = updv;   // reuse sn as the 'updates' row for GRU dots
    }
    __syncthreads();

    // ================= phase D: GRU + FF =================
    float hn = 0.f;
    if (wv < 8) {
      float h = slot_lds[wv][ln];
      float gi0 = bih[ln], gi1 = bih[64 + ln], gi2 = bih[128 + ln];
      float gh0 = bhh[ln], gh1 = bhh[64 + ln], gh2 = bhh[128 + ln];
      const float4* x4 = (const float4*)sn[wv];
      const float4* h4 = (const float4*)slot_lds[wv];
      const float4* wi0 = (const float4*)(wih + (size_t)ln * 64);
      const float4* wi1 = (const float4*)(wih + (size_t)(64 + ln) * 64);
      const float4* wi2 = (const float4*)(wih + (size_t)(128 + ln) * 64);
      const float4* wh0 = (const float4*)(whh + (size_t)ln * 64);
      const float4* wh1 = (const float4*)(whh + (size_t)(64 + ln) * 64);
      const float4* wh2 = (const float4*)(whh + (size_t)(128 + ln) * 64);
      #pragma unroll 4
      for (int c = 0; c < 16; ++c) {
        float4 xv = x4[c], hv = h4[c], a;
        a = wi0[c]; gi0 += xv.x * a.x + xv.y * a.y + xv.z * a.z + xv.w * a.w;
        a = wi1[c]; gi1 += xv.x * a.x + xv.y * a.y + xv.z * a.z + xv.w * a.w;
        a = wi2[c]; gi2 += xv.x * a.x + xv.y * a.y + xv.z * a.z + xv.w * a.w;
        a = wh0[c]; gh0 += hv.x * a.x + hv.y * a.y + hv.z * a.z + hv.w * a.w;
        a = wh1[c]; gh1 += hv.x * a.x + hv.y * a.y + hv.z * a.z + hv.w * a.w;
        a = wh2[c]; gh2 += hv.x * a.x + hv.y * a.y + hv.z * a.z + hv.w * a.w;
      }
      float r = 1.f / (1.f + expf(-(gi0 + gh0)));
      float z = 1.f / (1.f + expf(-(gi1 + gh1)));
      float n = tanhf(gi2 + r * gh2);
      hn = (1.f - z) * n + z * h;
      float s1 = hn, s2 = hn * hn;
      #pragma unroll
      for (int m = 32; m >= 1; m >>= 1) { s1 += __shfl_xor(s1, m, 64); s2 += __shfl_xor(s2, m, 64); }
      float mean = s1 * (1.f / 64.f);
      float var  = s2 * (1.f / 64.f) - mean * mean;
      ys[wv][ln] = (hn - mean) * rsqrtf(var + 1e-5f) * lnf_g[ln] + lnf_b[ln];
    }
    __syncthreads();
    if (wv < 8) {
      float a0 = fc1b[ln], a1 = fc1b[64 + ln];
      const float4* y4 = (const float4*)ys[wv];
      const float4* f0 = (const float4*)(fc1w + (size_t)ln * 64);
      const float4* f1 = (const float4*)(fc1w + (size_t)(64 + ln) * 64);
      #pragma unroll 4
      for (int c = 0; c < 16; ++c) {
        float4 yv = y4[c], a = f0[c], bb = f1[c];
        a0 += yv.x * a.x + yv.y * a.y + yv.z * a.z + yv.w * a.w;
        a1 += yv.x * bb.x + yv.y * bb.y + yv.z * bb.z + yv.w * bb.w;
      }
      rs[wv][ln] = fmaxf(a0, 0.f);
      rs[wv][64 + ln] = fmaxf(a1, 0.f);
    }
    __syncthreads();
    if (wv < 8) {
      float o = fc2b[ln];
      const float4* r4 = (const float4*)rs[wv];
      const float4* f2 = (const float4*)(fc2w + (size_t)ln * 128);
      #pragma unroll 4
      for (int c = 0; c < 32; ++c) {
        float4 rv = r4[c], a = f2[c];
        o += rv.x * a.x + rv.y * a.y + rv.z * a.z + rv.w * a.w;
      }
      slot_lds[wv][ln] = hn + o;
    }
    __syncthreads();
  }
  if (tid < 512) out_slots[(size_t)b * 512 + tid] = slot_lds[tid >> 6][ln];
}

// ---------------------------------------------------------------- launch
extern "C" void kernel_launch(void* const* d_in, const int* in_sizes, int n_in,
                              void* d_out, int out_size, void* d_ws, size_t ws_size,
                              hipStream_t stream) {
  const float* inputs = (const float*)d_in[0];
  const float* noise  = (const float*)d_in[1];
  const float* mu     = (const float*)d_in[2];
  const float* sigma  = (const float*)d_in[3];
  const float* Wq     = (const float*)d_in[4];
  const float* Wk     = (const float*)d_in[5];
  const float* Wv     = (const float*)d_in[6];
  const float* gwih   = (const float*)d_in[7];
  const float* gwhh   = (const float*)d_in[8];
  const float* gbih   = (const float*)d_in[9];
  const float* gbhh   = (const float*)d_in[10];
  const float* fc1w   = (const float*)d_in[11];
  const float* fc1b   = (const float*)d_in[12];
  const float* fc2w   = (const float*)d_in[13];
  const float* fc2b   = (const float*)d_in[14];
  const float* lnin_g = (const float*)d_in[15];
  const float* lnin_b = (const float*)d_in[16];
  const float* lns_g  = (const float*)d_in[17];
  const float* lns_b  = (const float*)d_in[18];
  const float* lnf_g  = (const float*)d_in[19];
  const float* lnf_b  = (const float*)d_in[20];
  const float* wi_w   = (const float*)d_in[21];
  const float* wi_b   = (const float*)d_in[22];
  const float* ws_w   = (const float*)d_in[23];
  const float* ws_b   = (const float*)d_in[24];

  float* out       = (float*)d_out;
  float* out_slots = out;                       // 256*8*64
  float* out_pos   = out + NB * NSL * ND;       // 256*8*2
  float* out_attn  = out_pos + NB * NSL * 2;    // 256*8*1024

  float* p = (float*)d_ws;
  float* xbuf  = p; p += (size_t)NB * NN * ND;  // 64 MB
  float* kkbuf = p; p += (size_t)NB * NN;
  float* wilog = p; p += (size_t)NB * NN;

  k_pre<<<(NB * NN) / 4, 256, 0, stream>>>(inputs, Wk, lnin_g, lnin_b, wi_w, wi_b,
                                           xbuf, kkbuf, wilog);
  k_mega<<<NB, 1024, 0, stream>>>(noise, mu, sigma, xbuf, kkbuf, wilog,
                                  Wq, Wk, Wv, gwih, gwhh, gbih, gbhh,
                                  fc1w, fc1b, fc2w, fc2b,
                                  lns_g, lns_b, lnf_g, lnf_b, ws_w, ws_b,
                                  out_slots, out_pos, out_attn);
}

// Round 6
// 1317.314 us; speedup vs baseline: 1.6575x; 1.0096x over previous
//
#include <hip/hip_runtime.h>
#include <math.h>

#define NB   256
#define NN   1024
#define ND   64
#define NSL  8
#define NHID 128
#define N_SINK 8
#define N_MESH 4
#define F_LR  3.0f
#define F_EPS 1e-8f

// ---------------------------------------------------------------- k_pre
// x = LN(inputs)*g+b ; kk = |x@Wk^T|^2 ; wilog = x . wi_w + wi_b
__global__ __launch_bounds__(256) void k_pre(
    const float* __restrict__ inp, const float* __restrict__ Wk,
    const float* __restrict__ lng, const float* __restrict__ lnb,
    const float* __restrict__ wiw, const float* __restrict__ wib,
    float* __restrict__ xout, float* __restrict__ kkout, float* __restrict__ wilog) {
  __shared__ __align__(16) float xs[4][64];
  int wv = threadIdx.x >> 6, ln = threadIdx.x & 63;
  size_t row = (size_t)blockIdx.x * 4 + wv;        // < 262144
  float xi = inp[row * 64 + ln];
  float s1 = xi, s2 = xi * xi;
  #pragma unroll
  for (int m = 32; m >= 1; m >>= 1) { s1 += __shfl_xor(s1, m, 64); s2 += __shfl_xor(s2, m, 64); }
  float mean = s1 * (1.f / 64.f);
  float var  = s2 * (1.f / 64.f) - mean * mean;
  float xn = (xi - mean) * rsqrtf(var + 1e-5f) * lng[ln] + lnb[ln];
  xs[wv][ln] = xn;
  xout[row * 64 + ln] = xn;
  float wl = xn * wiw[ln];
  #pragma unroll
  for (int m = 32; m >= 1; m >>= 1) wl += __shfl_xor(wl, m, 64);
  __syncthreads();
  const float4* w4 = (const float4*)(Wk + ln * 64);
  const float4* x4 = (const float4*)xs[wv];
  float ko = 0.f;
  #pragma unroll
  for (int c = 0; c < 16; ++c) {
    float4 a = w4[c], xv = x4[c];
    ko += a.x * xv.x + a.y * xv.y + a.z * xv.z + a.w * xv.w;
  }
  float kk = ko * ko;
  #pragma unroll
  for (int m = 32; m >= 1; m >>= 1) kk += __shfl_xor(kk, m, 64);
  if (ln == 0) { kkout[row] = kk; wilog[row] = wl + wib[0]; }
}

// ---------------------------------------------------------------- k_mega
// One block per batch. K (a.k.a. -C) lives in LDS as know[8][1024]:
//  - row threads read know[j][tid] (coalesced, 2-way = free)
//  - column-reducer waves 0-7 read know[wv][i] directly -> no transpose stores
//  - overwritten in place by P at the end (doubles as the attn tile)
// Register-resident hot-loop state is only Kbar[8]+temps, fitting the 64-VGPR
// budget the allocator forces on 1024-thread blocks (r2-r5: spill traffic).
__global__ __launch_bounds__(1024) void k_mega(
    const float* __restrict__ noise, const float* __restrict__ mu,
    const float* __restrict__ sigma,
    const float* __restrict__ xg, const float* __restrict__ kkg,
    const float* __restrict__ wilogg,
    const float* __restrict__ Wq, const float* __restrict__ Wk,
    const float* __restrict__ Wv,
    const float* __restrict__ wih, const float* __restrict__ whh,
    const float* __restrict__ bih, const float* __restrict__ bhh,
    const float* __restrict__ fc1w, const float* __restrict__ fc1b,
    const float* __restrict__ fc2w, const float* __restrict__ fc2b,
    const float* __restrict__ lns_g, const float* __restrict__ lns_b,
    const float* __restrict__ lnf_g, const float* __restrict__ lnf_b,
    const float* __restrict__ wsw, const float* __restrict__ wsb,
    float* __restrict__ out_slots, float* __restrict__ out_pos,
    float* __restrict__ out_attn) {
  __shared__ __align__(16) float know[8][NN];    // 32 KB: K matrix; later attn^T
  __shared__ __align__(16) union {
    float uhist[N_SINK][NN];    // phase B
    float part[16][8][64];      // phase C
  } U;
  __shared__ __align__(16) float dsb[NN];        // per-row dsum (backward)
  __shared__ __align__(16) float la_lds[NN];
  __shared__ __align__(16) float slot_lds[8][64];
  __shared__ __align__(16) float sn[8][64];      // slot LN; later updates row
  __shared__ __align__(16) float qsh[8][64];
  __shared__ __align__(16) float qs[8][64];
  __shared__ __align__(16) float updl[8][64];
  __shared__ __align__(16) float ys[8][64];
  __shared__ __align__(16) float rs[8][128];
  __shared__ float vbc[8];                       // current v (broadcast)
  __shared__ float vbarbc[8];                    // current vbar (broadcast)
  __shared__ float vhist[N_SINK][8];
  __shared__ float bmv[8], q2s[8], lbs[8];
  __shared__ float redf[16], bcf[1];

  int b = blockIdx.x, tid = threadIdx.x;
  int wv = tid >> 6, ln = tid & 63;

  // ---- slots init ----
  if (tid < 512) {
    slot_lds[tid >> 6][ln] = mu[ln] + (fabsf(sigma[ln]) + F_EPS) * noise[(size_t)b * 512 + tid];
  }
  // ---- la = log(8*softmax(wilog)+eps), block-wide ----
  float wl = wilogg[(size_t)b * NN + tid];
  float m0 = wl;
  #pragma unroll
  for (int s = 32; s >= 1; s >>= 1) m0 = fmaxf(m0, __shfl_xor(m0, s, 64));
  if (ln == 0) redf[wv] = m0;
  __syncthreads();
  if (tid == 0) { float a = redf[0]; for (int w = 1; w < 16; ++w) a = fmaxf(a, redf[w]); bcf[0] = a; }
  __syncthreads();
  m0 = bcf[0];
  float e0 = __expf(wl - m0), se0 = e0;
  #pragma unroll
  for (int s = 32; s >= 1; s >>= 1) se0 += __shfl_xor(se0, s, 64);
  __syncthreads();
  if (ln == 0) redf[wv] = se0;
  __syncthreads();
  if (tid == 0) { float a = 0.f; for (int w = 0; w < 16; ++w) a += redf[w]; bcf[0] = a; }
  __syncthreads();
  float la = __logf(8.f * e0 / bcf[0] + F_EPS);
  la_lds[tid] = la;
  float kk = kkg[(size_t)b * NN + tid];
  const float4* xrow4 = (const float4*)(xg + ((size_t)b * NN + tid) * ND);

  float u = 0.f;

  for (int it = 0; it < 3; ++it) {
    // ================= phase A: slotpre =================
    if (wv < 8) {
      float x = slot_lds[wv][ln];
      float s1 = x, s2 = x * x;
      #pragma unroll
      for (int m = 32; m >= 1; m >>= 1) { s1 += __shfl_xor(s1, m, 64); s2 += __shfl_xor(s2, m, 64); }
      float mean = s1 * (1.f / 64.f);
      float var  = s2 * (1.f / 64.f) - mean * mean;
      float xn = (x - mean) * rsqrtf(var + 1e-5f) * lns_g[ln] + lns_b[ln];
      sn[wv][ln] = xn;
      float wlg = xn * wsw[ln];
      #pragma unroll
      for (int m = 32; m >= 1; m >>= 1) wlg += __shfl_xor(wlg, m, 64);
      if (ln == 0) bmv[wv] = wlg + wsb[0];
    }
    __syncthreads();
    if (wv < 8) {
      const float4* w4 = (const float4*)(Wq + ln * 64);
      const float4* x4 = (const float4*)sn[wv];
      float q = 0.f;
      #pragma unroll
      for (int c = 0; c < 16; ++c) {
        float4 a = w4[c], xv = x4[c];
        q += a.x * xv.x + a.y * xv.y + a.z * xv.z + a.w * xv.w;
      }
      qsh[wv][ln] = q;
      float q2 = q * q;
      #pragma unroll
      for (int m = 32; m >= 1; m >>= 1) q2 += __shfl_xor(q2, m, 64);
      if (ln == 0) q2s[wv] = q2;
    }
    if (tid >= 512 && tid < 520) {   // lbs from bmv
      int j = tid - 512;
      float mx = bmv[0];
      #pragma unroll
      for (int jj = 1; jj < 8; ++jj) mx = fmaxf(mx, bmv[jj]);
      float ss = 0.f;
      #pragma unroll
      for (int jj = 0; jj < 8; ++jj) ss += __expf(bmv[jj] - mx);
      lbs[j] = __logf(8.f * __expf(bmv[j] - mx) / ss + F_EPS);
    }
    __syncthreads();
    if (wv < 8) {
      float qt = 0.f;
      for (int o = 0; o < 64; ++o) qt = fmaf(qsh[wv][o], Wk[o * 64 + ln], qt);
      qs[wv][ln] = qt;
    }
    __syncthreads();

    // ================= phase B: MESH + sinkhorn =================
    {
      float dot[8];
      #pragma unroll
      for (int j = 0; j < 8; ++j) dot[j] = 0.f;
      #pragma unroll 4
      for (int c = 0; c < 16; ++c) {
        float4 xv = xrow4[c];
        #pragma unroll
        for (int j = 0; j < 8; ++j) {
          const float4 qv = *(const float4*)&qs[j][c * 4];
          dot[j] += xv.x * qv.x + xv.y * qv.y + xv.z * qv.z + xv.w * qv.w;
        }
      }
      #pragma unroll
      for (int j = 0; j < 8; ++j) {
        float d2 = kk + q2s[j] - 2.f * dot[j];
        know[j][tid] = -sqrtf(fmaxf(d2, 1e-12f));
      }
    }
    for (int phase = 0; phase <= N_MESH; ++phase) {
      bool cold = (phase < N_MESH);
      // ---- forward: 8 sinkhorn iterations ----
      for (int t = 0; t < N_SINK; ++t) {
        bool z0 = cold && (t == 0);
        float kv[8];
        #pragma unroll
        for (int j = 0; j < 8; ++j) kv[j] = know[j][tid] + (z0 ? 0.f : vbc[j]);
        float mx = kv[0];
        #pragma unroll
        for (int j = 1; j < 8; ++j) mx = fmaxf(mx, kv[j]);
        float se = 0.f;
        #pragma unroll
        for (int j = 0; j < 8; ++j) se += __expf(kv[j] - mx);
        u = la - (mx + __logf(se));
        U.uhist[t][tid] = u;
        __syncthreads();
        if (wv < 8) {
          float tv[16];
          #pragma unroll
          for (int k = 0; k < 16; ++k) tv[k] = know[wv][ln + k * 64] + U.uhist[t][ln + k * 64];
          float M = tv[0];
          #pragma unroll
          for (int k = 1; k < 16; ++k) M = fmaxf(M, tv[k]);
          #pragma unroll
          for (int d = 32; d >= 1; d >>= 1) M = fmaxf(M, __shfl_xor(M, d, 64));
          float S = 0.f;
          #pragma unroll
          for (int k = 0; k < 16; ++k) S += __expf(tv[k] - M);
          #pragma unroll
          for (int d = 32; d >= 1; d >>= 1) S += __shfl_xor(S, d, 64);
          if (ln == 0) {
            float vj = lbs[wv] - (M + __logf(S));
            vbc[wv] = vj; vhist[t][wv] = vj;
          }
        }
        __syncthreads();
      }
      if (phase == N_MESH) break;

      // ---- backward: dH/dK ----
      float Kbar[8], ubarT;
      {
        float gsum = 0.f;
        #pragma unroll
        for (int j = 0; j < 8; ++j) {
          float P  = __expf(know[j][tid] + u + vbc[j]);
          float pe = P + F_EPS;
          float gp = -(__logf(pe) + P / pe) * P;
          Kbar[j] = gp; gsum += gp;
        }
        ubarT = gsum;
      }
      if (wv < 8) {   // vbar init: column sums of G*P, recomputed locally
        float vj = vbc[wv];
        float S = 0.f;
        #pragma unroll
        for (int k = 0; k < 16; ++k) {
          int i = ln + k * 64;
          float P  = __expf(know[wv][i] + U.uhist[N_SINK - 1][i] + vj);
          float pe = P + F_EPS;
          S += -(__logf(pe) + P / pe) * P;
        }
        #pragma unroll
        for (int d = 32; d >= 1; d >>= 1) S += __shfl_xor(S, d, 64);
        if (ln == 0) vbarbc[wv] = S;
      }
      __syncthreads();
      for (int t = N_SINK - 1; t >= 0; --t) {
        float ut = U.uhist[t][tid];
        float dsum = (t == N_SINK - 1) ? ubarT : 0.f;
        #pragma unroll
        for (int j = 0; j < 8; ++j) {
          float w  = __expf(know[j][tid] + ut + vhist[t][j] - lbs[j]);
          float vw = vbarbc[j] * w;
          Kbar[j] -= vw; dsum -= vw;
        }
        #pragma unroll
        for (int j = 0; j < 8; ++j) {
          float vprev = (t > 0) ? vhist[t - 1][j] : 0.f;
          float z  = __expf(know[j][tid] + vprev + ut - la);
          Kbar[j] -= dsum * z;
        }
        if (t > 0) {
          dsb[tid] = dsum;
          __syncthreads();
          if (wv < 8) {
            float vp = vhist[t - 1][wv];
            float S = 0.f;
            #pragma unroll
            for (int k = 0; k < 16; ++k) {
              int i = ln + k * 64;
              float z = __expf(know[wv][i] + vp + U.uhist[t][i] - la_lds[i]);
              S += dsb[i] * z;
            }
            #pragma unroll
            for (int d = 32; d >= 1; d >>= 1) S += __shfl_xor(S, d, 64);
            if (ln == 0) vbarbc[wv] = -S;
          }
          __syncthreads();
        }
      }
      // K <- K - lr*Kbar (own column, no barrier needed before next u-step)
      #pragma unroll
      for (int j = 0; j < 8; ++j) know[j][tid] -= F_LR * Kbar[j];
    }
    // ---- P = exp(K+u+v), in place (know becomes attn^T) ----
    #pragma unroll
    for (int j = 0; j < 8; ++j) {
      float P = __expf(know[j][tid] + u + vbc[j]);
      know[j][tid] = P;
      if (it == 2) out_attn[((size_t)b * 8 + j) * NN + tid] = P;
    }
    __syncthreads();

    // ================= phase C: updates =================
    {
      float acc[8];
      #pragma unroll
      for (int j = 0; j < 8; ++j) acc[j] = 0.f;
      const float* xc = xg + ((size_t)b * NN + wv * 64) * ND + ln;
      #pragma unroll 2
      for (int i0 = 0; i0 < 64; i0 += 4) {
        float x0 = xc[(size_t)(i0 + 0) * 64];
        float x1 = xc[(size_t)(i0 + 1) * 64];
        float x2 = xc[(size_t)(i0 + 2) * 64];
        float x3 = xc[(size_t)(i0 + 3) * 64];
        int ir = wv * 64 + i0;
        #pragma unroll
        for (int j = 0; j < 8; ++j) {
          float4 a = *(const float4*)&know[j][ir];
          acc[j] += a.x * x0 + a.y * x1 + a.z * x2 + a.w * x3;
        }
      }
      #pragma unroll
      for (int j = 0; j < 8; ++j) U.part[wv][j][ln] = acc[j];
    }
    if (it == 2 && wv < 8) {   // slot_pos from final attn
      float px = 0.f, py = 0.f;
      #pragma unroll
      for (int k = 0; k < 16; ++k) {
        int i = ln + k * 64;
        float a = know[wv][i];
        px += a * (float)(i & 31);
        py += a * (float)(i >> 5);
      }
      #pragma unroll
      for (int m = 32; m >= 1; m >>= 1) { px += __shfl_xor(px, m, 64); py += __shfl_xor(py, m, 64); }
      if (ln == 0) {
        out_pos[(b * 8 + wv) * 2 + 0] = px * (1.f / 31.f);
        out_pos[(b * 8 + wv) * 2 + 1] = py * (1.f / 31.f);
      }
    }
    __syncthreads();
    if (wv < 8) {
      float s = 0.f;
      #pragma unroll
      for (int w = 0; w < 16; ++w) s += U.part[w][wv][ln];
      updl[wv][ln] = s;
    }
    __syncthreads();
    if (wv < 8) {
      const float4* w4 = (const float4*)(Wv + ln * 64);
      const float4* u4 = (const float4*)updl[wv];
      float updv = 0.f;
      #pragma unroll
      for (int c = 0; c < 16; ++c) {
        float4 uv = u4[c], wvv = w4[c];
        updv += uv.x * wvv.x + uv.y * wvv.y + uv.z * wvv.z + uv.w * wvv.w;
      }
      sn[wv][ln] = updv;   // reuse sn as the 'updates' row for GRU dots
    }
    __syncthreads();

    // ================= phase D: GRU + FF =================
    float hn = 0.f;
    if (wv < 8) {
      float h = slot_lds[wv][ln];
      float gi0 = bih[ln], gi1 = bih[64 + ln], gi2 = bih[128 + ln];
      float gh0 = bhh[ln], gh1 = bhh[64 + ln], gh2 = bhh[128 + ln];
      const float4* x4 = (const float4*)sn[wv];
      const float4* h4 = (const float4*)slot_lds[wv];
      const float4* wi0 = (const float4*)(wih + (size_t)ln * 64);
      const float4* wi1 = (const float4*)(wih + (size_t)(64 + ln) * 64);
      const float4* wi2 = (const float4*)(wih + (size_t)(128 + ln) * 64);
      const float4* wh0 = (const float4*)(whh + (size_t)ln * 64);
      const float4* wh1 = (const float4*)(whh + (size_t)(64 + ln) * 64);
      const float4* wh2 = (const float4*)(whh + (size_t)(128 + ln) * 64);
      #pragma unroll 2
      for (int c = 0; c < 16; ++c) {
        float4 xv = x4[c], hv = h4[c], a;
        a = wi0[c]; gi0 += xv.x * a.x + xv.y * a.y + xv.z * a.z + xv.w * a.w;
        a = wi1[c]; gi1 += xv.x * a.x + xv.y * a.y + xv.z * a.z + xv.w * a.w;
        a = wi2[c]; gi2 += xv.x * a.x + xv.y * a.y + xv.z * a.z + xv.w * a.w;
        a = wh0[c]; gh0 += hv.x * a.x + hv.y * a.y + hv.z * a.z + hv.w * a.w;
        a = wh1[c]; gh1 += hv.x * a.x + hv.y * a.y + hv.z * a.z + hv.w * a.w;
        a = wh2[c]; gh2 += hv.x * a.x + hv.y * a.y + hv.z * a.z + hv.w * a.w;
      }
      float r = 1.f / (1.f + expf(-(gi0 + gh0)));
      float z = 1.f / (1.f + expf(-(gi1 + gh1)));
      float n = tanhf(gi2 + r * gh2);
      hn = (1.f - z) * n + z * h;
      float s1 = hn, s2 = hn * hn;
      #pragma unroll
      for (int m = 32; m >= 1; m >>= 1) { s1 += __shfl_xor(s1, m, 64); s2 += __shfl_xor(s2, m, 64); }
      float mean = s1 * (1.f / 64.f);
      float var  = s2 * (1.f / 64.f) - mean * mean;
      ys[wv][ln] = (hn - mean) * rsqrtf(var + 1e-5f) * lnf_g[ln] + lnf_b[ln];
    }
    __syncthreads();
    if (wv < 8) {
      float a0 = fc1b[ln], a1 = fc1b[64 + ln];
      const float4* y4 = (const float4*)ys[wv];
      const float4* f0 = (const float4*)(fc1w + (size_t)ln * 64);
      const float4* f1 = (const float4*)(fc1w + (size_t)(64 + ln) * 64);
      #pragma unroll 2
      for (int c = 0; c < 16; ++c) {
        float4 yv = y4[c], a = f0[c], bb = f1[c];
        a0 += yv.x * a.x + yv.y * a.y + yv.z * a.z + yv.w * a.w;
        a1 += yv.x * bb.x + yv.y * bb.y + yv.z * bb.z + yv.w * bb.w;
      }
      rs[wv][ln] = fmaxf(a0, 0.f);
      rs[wv][64 + ln] = fmaxf(a1, 0.f);
    }
    __syncthreads();
    if (wv < 8) {
      float o = fc2b[ln];
      const float4* r4 = (const float4*)rs[wv];
      const float4* f2 = (const float4*)(fc2w + (size_t)ln * 128);
      #pragma unroll 2
      for (int c = 0; c < 32; ++c) {
        float4 rv = r4[c], a = f2[c];
        o += rv.x * a.x + rv.y * a.y + rv.z * a.z + rv.w * a.w;
      }
      slot_lds[wv][ln] = hn + o;
    }
    __syncthreads();
  }
  if (tid < 512) out_slots[(size_t)b * 512 + tid] = slot_lds[tid >> 6][ln];
}

// ---------------------------------------------------------------- launch
extern "C" void kernel_launch(void* const* d_in, const int* in_sizes, int n_in,
                              void* d_out, int out_size, void* d_ws, size_t ws_size,
                              hipStream_t stream) {
  const float* inputs = (const float*)d_in[0];
  const float* noise  = (const float*)d_in[1];
  const float* mu     = (const float*)d_in[2];
  const float* sigma  = (const float*)d_in[3];
  const float* Wq     = (const float*)d_in[4];
  const float* Wk     = (const float*)d_in[5];
  const float* Wv     = (const float*)d_in[6];
  const float* gwih   = (const float*)d_in[7];
  const float* gwhh   = (const float*)d_in[8];
  const float* gbih   = (const float*)d_in[9];
  const float* gbhh   = (const float*)d_in[10];
  const float* fc1w   = (const float*)d_in[11];
  const float* fc1b   = (const float*)d_in[12];
  const float* fc2w   = (const float*)d_in[13];
  const float* fc2b   = (const float*)d_in[14];
  const float* lnin_g = (const float*)d_in[15];
  const float* lnin_b = (const float*)d_in[16];
  const float* lns_g  = (const float*)d_in[17];
  const float* lns_b  = (const float*)d_in[18];
  const float* lnf_g  = (const float*)d_in[19];
  const float* lnf_b  = (const float*)d_in[20];
  const float* wi_w   = (const float*)d_in[21];
  const float* wi_b   = (const float*)d_in[22];
  const float* ws_w   = (const float*)d_in[23];
  const float* ws_b   = (const float*)d_in[24];

  float* out       = (float*)d_out;
  float* out_slots = out;                       // 256*8*64
  float* out_pos   = out + NB * NSL * ND;       // 256*8*2
  float* out_attn  = out_pos + NB * NSL * 2;    // 256*8*1024

  float* p = (float*)d_ws;
  float* xbuf  = p; p += (size_t)NB * NN * ND;  // 64 MB
  float* kkbuf = p; p += (size_t)NB * NN;
  float* wilog = p; p += (size_t)NB * NN;

  k_pre<<<(NB * NN) / 4, 256, 0, stream>>>(inputs, Wk, lnin_g, lnin_b, wi_w, wi_b,
                                           xbuf, kkbuf, wilog);
  k_mega<<<NB, 1024, 0, stream>>>(noise, mu, sigma, xbuf, kkbuf, wilog,
                                  Wq, Wk, Wv, gwih, gwhh, gbih, gbhh,
                                  fc1w, fc1b, fc2w, fc2b,
                                  lns_g, lns_b, lnf_g, lnf_b, ws_w, ws_b,
                                  out_slots, out_pos, out_attn);
}

// Round 7
// 1109.429 us; speedup vs baseline: 1.9681x; 1.1874x over previous
//
#include <hip/hip_runtime.h>
#include <math.h>

#define NB   256
#define NN   1024
#define ND   64
#define NSL  8
#define NHID 128
#define N_SINK 8
#define N_MESH 4
#define F_LR  3.0f
#define F_EPS 1e-8f

// ---------------------------------------------------------------- k_pre
// x = LN(inputs)*g+b ; kk = |x@Wk^T|^2 ; wilog = x . wi_w + wi_b
__global__ __launch_bounds__(256) void k_pre(
    const float* __restrict__ inp, const float* __restrict__ Wk,
    const float* __restrict__ lng, const float* __restrict__ lnb,
    const float* __restrict__ wiw, const float* __restrict__ wib,
    float* __restrict__ xout, float* __restrict__ kkout, float* __restrict__ wilog) {
  __shared__ __align__(16) float xs[4][64];
  int wv = threadIdx.x >> 6, ln = threadIdx.x & 63;
  size_t row = (size_t)blockIdx.x * 4 + wv;        // < 262144
  float xi = inp[row * 64 + ln];
  float s1 = xi, s2 = xi * xi;
  #pragma unroll
  for (int m = 32; m >= 1; m >>= 1) { s1 += __shfl_xor(s1, m, 64); s2 += __shfl_xor(s2, m, 64); }
  float mean = s1 * (1.f / 64.f);
  float var  = s2 * (1.f / 64.f) - mean * mean;
  float xn = (xi - mean) * rsqrtf(var + 1e-5f) * lng[ln] + lnb[ln];
  xs[wv][ln] = xn;
  xout[row * 64 + ln] = xn;
  float wl = xn * wiw[ln];
  #pragma unroll
  for (int m = 32; m >= 1; m >>= 1) wl += __shfl_xor(wl, m, 64);
  __syncthreads();
  const float4* w4 = (const float4*)(Wk + ln * 64);
  const float4* x4 = (const float4*)xs[wv];
  float ko = 0.f;
  #pragma unroll
  for (int c = 0; c < 16; ++c) {
    float4 a = w4[c], xv = x4[c];
    ko += a.x * xv.x + a.y * xv.y + a.z * xv.z + a.w * xv.w;
  }
  float kk = ko * ko;
  #pragma unroll
  for (int m = 32; m >= 1; m >>= 1) kk += __shfl_xor(kk, m, 64);
  if (ln == 0) { kkout[row] = kk; wilog[row] = wl + wib[0]; }
}

// ---------------------------------------------------------------- k_mega
// Multiplicative-domain Sinkhorn: M=exp(K) lives in LDS know[8][1024] and in
// registers Mreg[8]; f=exp(u), g=exp(v). Forward and backward loops are
// fma-only (no exp/log); transcendentals only at M init/update and entropy
// head. Peak register demand ~45 -> fits the 64-VGPR budget, no spills.
__global__ __launch_bounds__(1024) void k_mega(
    const float* __restrict__ noise, const float* __restrict__ mu,
    const float* __restrict__ sigma,
    const float* __restrict__ xg, const float* __restrict__ kkg,
    const float* __restrict__ wilogg,
    const float* __restrict__ Wq, const float* __restrict__ Wk,
    const float* __restrict__ Wv,
    const float* __restrict__ wih, const float* __restrict__ whh,
    const float* __restrict__ bih, const float* __restrict__ bhh,
    const float* __restrict__ fc1w, const float* __restrict__ fc1b,
    const float* __restrict__ fc2w, const float* __restrict__ fc2b,
    const float* __restrict__ lns_g, const float* __restrict__ lns_b,
    const float* __restrict__ lnf_g, const float* __restrict__ lnf_b,
    const float* __restrict__ wsw, const float* __restrict__ wsb,
    float* __restrict__ out_slots, float* __restrict__ out_pos,
    float* __restrict__ out_attn) {
  __shared__ __align__(16) float know[8][NN];    // 32 KB: M matrix; later attn^T
  __shared__ __align__(16) union {
    float fhist[N_SINK][NN];    // phase B (f = exp(u) history)
    float part[16][8][64];      // phase C
  } U;
  __shared__ __align__(16) float dsb[NN];        // per-row dsum*f*rA (backward)
  __shared__ __align__(16) float slot_lds[8][64];
  __shared__ __align__(16) float sn[8][64];      // slot LN; later updates row
  __shared__ __align__(16) float qsh[8][64];
  __shared__ __align__(16) float qs[8][64];
  __shared__ __align__(16) float updl[8][64];
  __shared__ __align__(16) float ys[8][64];
  __shared__ __align__(16) float rs[8][128];
  __shared__ float gbc[8];                       // current g (broadcast)
  __shared__ float vbarbc[8];                    // current vbar (broadcast)
  __shared__ float ghist[N_SINK][8];             // g history
  __shared__ float gBh[N_SINK][8];               // g/B history
  __shared__ float bmv[8], q2s[8], Bs[8], rBs[8];
  __shared__ float redf[16], bcf[1];

  int b = blockIdx.x, tid = threadIdx.x;
  int wv = tid >> 6, ln = tid & 63;

  // ---- slots init ----
  if (tid < 512) {
    slot_lds[tid >> 6][ln] = mu[ln] + (fabsf(sigma[ln]) + F_EPS) * noise[(size_t)b * 512 + tid];
  }
  // ---- A_i = 8*softmax(wilog)+eps, block-wide ----
  float wl = wilogg[(size_t)b * NN + tid];
  float m0 = wl;
  #pragma unroll
  for (int s = 32; s >= 1; s >>= 1) m0 = fmaxf(m0, __shfl_xor(m0, s, 64));
  if (ln == 0) redf[wv] = m0;
  __syncthreads();
  if (tid == 0) { float a = redf[0]; for (int w = 1; w < 16; ++w) a = fmaxf(a, redf[w]); bcf[0] = a; }
  __syncthreads();
  m0 = bcf[0];
  float e0 = __expf(wl - m0), se0 = e0;
  #pragma unroll
  for (int s = 32; s >= 1; s >>= 1) se0 += __shfl_xor(se0, s, 64);
  __syncthreads();
  if (ln == 0) redf[wv] = se0;
  __syncthreads();
  if (tid == 0) { float a = 0.f; for (int w = 0; w < 16; ++w) a += redf[w]; bcf[0] = a; }
  __syncthreads();
  float Ai  = 8.f * e0 / bcf[0] + F_EPS;
  float rAi = __frcp_rn(Ai);
  float kk = kkg[(size_t)b * NN + tid];
  const float4* xrow4 = (const float4*)(xg + ((size_t)b * NN + tid) * ND);

  for (int it = 0; it < 3; ++it) {
    // ================= phase A: slotpre =================
    if (wv < 8) {
      float x = slot_lds[wv][ln];
      float s1 = x, s2 = x * x;
      #pragma unroll
      for (int m = 32; m >= 1; m >>= 1) { s1 += __shfl_xor(s1, m, 64); s2 += __shfl_xor(s2, m, 64); }
      float mean = s1 * (1.f / 64.f);
      float var  = s2 * (1.f / 64.f) - mean * mean;
      float xn = (x - mean) * rsqrtf(var + 1e-5f) * lns_g[ln] + lns_b[ln];
      sn[wv][ln] = xn;
      float wlg = xn * wsw[ln];
      #pragma unroll
      for (int m = 32; m >= 1; m >>= 1) wlg += __shfl_xor(wlg, m, 64);
      if (ln == 0) bmv[wv] = wlg + wsb[0];
    }
    __syncthreads();
    if (wv < 8) {
      const float4* w4 = (const float4*)(Wq + ln * 64);
      const float4* x4 = (const float4*)sn[wv];
      float q = 0.f;
      #pragma unroll
      for (int c = 0; c < 16; ++c) {
        float4 a = w4[c], xv = x4[c];
        q += a.x * xv.x + a.y * xv.y + a.z * xv.z + a.w * xv.w;
      }
      qsh[wv][ln] = q;
      float q2 = q * q;
      #pragma unroll
      for (int m = 32; m >= 1; m >>= 1) q2 += __shfl_xor(q2, m, 64);
      if (ln == 0) q2s[wv] = q2;
    }
    if (tid >= 512 && tid < 520) {   // B_j = 8*softmax(bmv)+eps
      int j = tid - 512;
      float mx = bmv[0];
      #pragma unroll
      for (int jj = 1; jj < 8; ++jj) mx = fmaxf(mx, bmv[jj]);
      float ss = 0.f;
      #pragma unroll
      for (int jj = 0; jj < 8; ++jj) ss += __expf(bmv[jj] - mx);
      float Bj = 8.f * __expf(bmv[j] - mx) / ss + F_EPS;
      Bs[j] = Bj; rBs[j] = __frcp_rn(Bj);
    }
    __syncthreads();
    if (wv < 8) {
      float qt = 0.f;
      for (int o = 0; o < 64; ++o) qt = fmaf(qsh[wv][o], Wk[o * 64 + ln], qt);
      qs[wv][ln] = qt;
    }
    __syncthreads();

    // ================= phase B: MESH + sinkhorn (multiplicative) =========
    float Mreg[8];
    {
      float dot[8];
      #pragma unroll
      for (int j = 0; j < 8; ++j) dot[j] = 0.f;
      #pragma unroll 4
      for (int c = 0; c < 16; ++c) {
        float4 xv = xrow4[c];
        #pragma unroll
        for (int j = 0; j < 8; ++j) {
          const float4 qv = *(const float4*)&qs[j][c * 4];
          dot[j] += xv.x * qv.x + xv.y * qv.y + xv.z * qv.z + xv.w * qv.w;
        }
      }
      #pragma unroll
      for (int j = 0; j < 8; ++j) {
        float d2 = kk + q2s[j] - 2.f * dot[j];
        float K = -sqrtf(fmaxf(d2, 1e-12f));
        Mreg[j] = __expf(K);
        know[j][tid] = Mreg[j];
      }
    }
    float f = 0.f;
    for (int phase = 0; phase <= N_MESH; ++phase) {
      bool cold = (phase < N_MESH);
      // ---- forward: 8 sinkhorn iterations, fma-only ----
      for (int t = 0; t < N_SINK; ++t) {
        float se = 0.f;
        if (cold && t == 0) {
          #pragma unroll
          for (int j = 0; j < 8; ++j) se += Mreg[j];
        } else {
          #pragma unroll
          for (int j = 0; j < 8; ++j) se += Mreg[j] * gbc[j];
        }
        f = __fdividef(Ai, se);
        U.fhist[t][tid] = f;
        __syncthreads();
        if (wv < 8) {
          float S = 0.f;
          #pragma unroll
          for (int k = 0; k < 16; ++k) {
            int i = ln + k * 64;
            S += know[wv][i] * U.fhist[t][i];
          }
          #pragma unroll
          for (int d = 32; d >= 1; d >>= 1) S += __shfl_xor(S, d, 64);
          if (ln == 0) {
            float g = __fdividef(Bs[wv], S);
            gbc[wv] = g; ghist[t][wv] = g; gBh[t][wv] = g * rBs[wv];
          }
        }
        __syncthreads();
      }
      if (phase == N_MESH) break;

      // ---- backward: dH/dK (fma-only t-loop) ----
      float Kbar[8], ubarT;
      {
        float gsum = 0.f;
        #pragma unroll
        for (int j = 0; j < 8; ++j) {
          float P  = Mreg[j] * f * gbc[j];
          float pe = P + F_EPS;
          float gp = -(__logf(pe) + __fdividef(P, pe)) * P;
          Kbar[j] = gp; gsum += gp;
        }
        ubarT = gsum;
      }
      if (wv < 8) {   // vbar init: column sums of G*P
        float gw = gbc[wv];
        float S = 0.f;
        #pragma unroll
        for (int k = 0; k < 16; ++k) {
          int i = ln + k * 64;
          float P  = know[wv][i] * U.fhist[N_SINK - 1][i] * gw;
          float pe = P + F_EPS;
          S += -(__logf(pe) + __fdividef(P, pe)) * P;
        }
        #pragma unroll
        for (int d = 32; d >= 1; d >>= 1) S += __shfl_xor(S, d, 64);
        if (ln == 0) vbarbc[wv] = S;
      }
      __syncthreads();
      for (int t = N_SINK - 1; t >= 0; --t) {
        float ft = U.fhist[t][tid];
        float dsum = (t == N_SINK - 1) ? ubarT : 0.f;
        #pragma unroll
        for (int j = 0; j < 8; ++j) {
          float vw = vbarbc[j] * gBh[t][j] * (Mreg[j] * ft);
          Kbar[j] -= vw; dsum -= vw;
        }
        float dfa = dsum * ft * rAi;
        if (t > 0) {
          #pragma unroll
          for (int j = 0; j < 8; ++j) Kbar[j] -= dfa * Mreg[j] * ghist[t - 1][j];
          dsb[tid] = dfa;
          __syncthreads();
          if (wv < 8) {
            float S = 0.f;
            #pragma unroll
            for (int k = 0; k < 16; ++k) {
              int i = ln + k * 64;
              S += know[wv][i] * dsb[i];
            }
            #pragma unroll
            for (int d = 32; d >= 1; d >>= 1) S += __shfl_xor(S, d, 64);
            if (ln == 0) vbarbc[wv] = -ghist[t - 1][wv] * S;
          }
          __syncthreads();
        } else {
          #pragma unroll
          for (int j = 0; j < 8; ++j) Kbar[j] -= dfa * Mreg[j];   // g_prev = 1
        }
      }
      // M <- M * exp(-lr*Kbar); own column, next read is after a barrier
      #pragma unroll
      for (int j = 0; j < 8; ++j) {
        Mreg[j] *= __expf(-F_LR * Kbar[j]);
        know[j][tid] = Mreg[j];
      }
    }
    // ---- P = M*f*g, in place (know becomes attn^T) ----
    #pragma unroll
    for (int j = 0; j < 8; ++j) {
      float P = Mreg[j] * f * gbc[j];
      know[j][tid] = P;
      if (it == 2) out_attn[((size_t)b * 8 + j) * NN + tid] = P;
    }
    __syncthreads();

    // ================= phase C: updates =================
    {
      float acc[8];
      #pragma unroll
      for (int j = 0; j < 8; ++j) acc[j] = 0.f;
      const float* xc = xg + ((size_t)b * NN + wv * 64) * ND + ln;
      #pragma unroll 2
      for (int i0 = 0; i0 < 64; i0 += 4) {
        float x0 = xc[(size_t)(i0 + 0) * 64];
        float x1 = xc[(size_t)(i0 + 1) * 64];
        float x2 = xc[(size_t)(i0 + 2) * 64];
        float x3 = xc[(size_t)(i0 + 3) * 64];
        int ir = wv * 64 + i0;
        #pragma unroll
        for (int j = 0; j < 8; ++j) {
          float4 a = *(const float4*)&know[j][ir];
          acc[j] += a.x * x0 + a.y * x1 + a.z * x2 + a.w * x3;
        }
      }
      #pragma unroll
      for (int j = 0; j < 8; ++j) U.part[wv][j][ln] = acc[j];
    }
    if (it == 2 && wv < 8) {   // slot_pos from final attn
      float px = 0.f, py = 0.f;
      #pragma unroll
      for (int k = 0; k < 16; ++k) {
        int i = ln + k * 64;
        float a = know[wv][i];
        px += a * (float)(i & 31);
        py += a * (float)(i >> 5);
      }
      #pragma unroll
      for (int m = 32; m >= 1; m >>= 1) { px += __shfl_xor(px, m, 64); py += __shfl_xor(py, m, 64); }
      if (ln == 0) {
        out_pos[(b * 8 + wv) * 2 + 0] = px * (1.f / 31.f);
        out_pos[(b * 8 + wv) * 2 + 1] = py * (1.f / 31.f);
      }
    }
    __syncthreads();
    if (wv < 8) {
      float s = 0.f;
      #pragma unroll
      for (int w = 0; w < 16; ++w) s += U.part[w][wv][ln];
      updl[wv][ln] = s;
    }
    __syncthreads();
    if (wv < 8) {
      const float4* w4 = (const float4*)(Wv + ln * 64);
      const float4* u4 = (const float4*)updl[wv];
      float updv = 0.f;
      #pragma unroll
      for (int c = 0; c < 16; ++c) {
        float4 uv = u4[c], wvv = w4[c];
        updv += uv.x * wvv.x + uv.y * wvv.y + uv.z * wvv.z + uv.w * wvv.w;
      }
      sn[wv][ln] = updv;   // reuse sn as the 'updates' row for GRU dots
    }
    __syncthreads();

    // ================= phase D: GRU + FF =================
    float hn = 0.f;
    if (wv < 8) {
      float h = slot_lds[wv][ln];
      float gi0 = bih[ln], gi1 = bih[64 + ln], gi2 = bih[128 + ln];
      float gh0 = bhh[ln], gh1 = bhh[64 + ln], gh2 = bhh[128 + ln];
      const float4* x4 = (const float4*)sn[wv];
      const float4* h4 = (const float4*)slot_lds[wv];
      const float4* wi0 = (const float4*)(wih + (size_t)ln * 64);
      const float4* wi1 = (const float4*)(wih + (size_t)(64 + ln) * 64);
      const float4* wi2 = (const float4*)(wih + (size_t)(128 + ln) * 64);
      const float4* wh0 = (const float4*)(whh + (size_t)ln * 64);
      const float4* wh1 = (const float4*)(whh + (size_t)(64 + ln) * 64);
      const float4* wh2 = (const float4*)(whh + (size_t)(128 + ln) * 64);
      #pragma unroll 2
      for (int c = 0; c < 16; ++c) {
        float4 xv = x4[c], hv = h4[c], a;
        a = wi0[c]; gi0 += xv.x * a.x + xv.y * a.y + xv.z * a.z + xv.w * a.w;
        a = wi1[c]; gi1 += xv.x * a.x + xv.y * a.y + xv.z * a.z + xv.w * a.w;
        a = wi2[c]; gi2 += xv.x * a.x + xv.y * a.y + xv.z * a.z + xv.w * a.w;
        a = wh0[c]; gh0 += hv.x * a.x + hv.y * a.y + hv.z * a.z + hv.w * a.w;
        a = wh1[c]; gh1 += hv.x * a.x + hv.y * a.y + hv.z * a.z + hv.w * a.w;
        a = wh2[c]; gh2 += hv.x * a.x + hv.y * a.y + hv.z * a.z + hv.w * a.w;
      }
      float r = 1.f / (1.f + expf(-(gi0 + gh0)));
      float z = 1.f / (1.f + expf(-(gi1 + gh1)));
      float n = tanhf(gi2 + r * gh2);
      hn = (1.f - z) * n + z * h;
      float s1 = hn, s2 = hn * hn;
      #pragma unroll
      for (int m = 32; m >= 1; m >>= 1) { s1 += __shfl_xor(s1, m, 64); s2 += __shfl_xor(s2, m, 64); }
      float mean = s1 * (1.f / 64.f);
      float var  = s2 * (1.f / 64.f) - mean * mean;
      ys[wv][ln] = (hn - mean) * rsqrtf(var + 1e-5f) * lnf_g[ln] + lnf_b[ln];
    }
    __syncthreads();
    if (wv < 8) {
      float a0 = fc1b[ln], a1 = fc1b[64 + ln];
      const float4* y4 = (const float4*)ys[wv];
      const float4* f0 = (const float4*)(fc1w + (size_t)ln * 64);
      const float4* f1 = (const float4*)(fc1w + (size_t)(64 + ln) * 64);
      #pragma unroll 2
      for (int c = 0; c < 16; ++c) {
        float4 yv = y4[c], a = f0[c], bb = f1[c];
        a0 += yv.x * a.x + yv.y * a.y + yv.z * a.z + yv.w * a.w;
        a1 += yv.x * bb.x + yv.y * bb.y + yv.z * bb.z + yv.w * bb.w;
      }
      rs[wv][ln] = fmaxf(a0, 0.f);
      rs[wv][64 + ln] = fmaxf(a1, 0.f);
    }
    __syncthreads();
    if (wv < 8) {
      float o = fc2b[ln];
      const float4* r4 = (const float4*)rs[wv];
      const float4* f2 = (const float4*)(fc2w + (size_t)ln * 128);
      #pragma unroll 2
      for (int c = 0; c < 32; ++c) {
        float4 rv = r4[c], a = f2[c];
        o += rv.x * a.x + rv.y * a.y + rv.z * a.z + rv.w * a.w;
      }
      slot_lds[wv][ln] = hn + o;
    }
    __syncthreads();
  }
  if (tid < 512) out_slots[(size_t)b * 512 + tid] = slot_lds[tid >> 6][ln];
}

// ---------------------------------------------------------------- launch
extern "C" void kernel_launch(void* const* d_in, const int* in_sizes, int n_in,
                              void* d_out, int out_size, void* d_ws, size_t ws_size,
                              hipStream_t stream) {
  const float* inputs = (const float*)d_in[0];
  const float* noise  = (const float*)d_in[1];
  const float* mu     = (const float*)d_in[2];
  const float* sigma  = (const float*)d_in[3];
  const float* Wq     = (const float*)d_in[4];
  const float* Wk     = (const float*)d_in[5];
  const float* Wv     = (const float*)d_in[6];
  const float* gwih   = (const float*)d_in[7];
  const float* gwhh   = (const float*)d_in[8];
  const float* gbih   = (const float*)d_in[9];
  const float* gbhh   = (const float*)d_in[10];
  const float* fc1w   = (const float*)d_in[11];
  const float* fc1b   = (const float*)d_in[12];
  const float* fc2w   = (const float*)d_in[13];
  const float* fc2b   = (const float*)d_in[14];
  const float* lnin_g = (const float*)d_in[15];
  const float* lnin_b = (const float*)d_in[16];
  const float* lns_g  = (const float*)d_in[17];
  const float* lns_b  = (const float*)d_in[18];
  const float* lnf_g  = (const float*)d_in[19];
  const float* lnf_b  = (const float*)d_in[20];
  const float* wi_w   = (const float*)d_in[21];
  const float* wi_b   = (const float*)d_in[22];
  const float* ws_w   = (const float*)d_in[23];
  const float* ws_b   = (const float*)d_in[24];

  float* out       = (float*)d_out;
  float* out_slots = out;                       // 256*8*64
  float* out_pos   = out + NB * NSL * ND;       // 256*8*2
  float* out_attn  = out_pos + NB * NSL * 2;    // 256*8*1024

  float* p = (float*)d_ws;
  float* xbuf  = p; p += (size_t)NB * NN * ND;  // 64 MB
  float* kkbuf = p; p += (size_t)NB * NN;
  float* wilog = p; p += (size_t)NB * NN;

  k_pre<<<(NB * NN) / 4, 256, 0, stream>>>(inputs, Wk, lnin_g, lnin_b, wi_w, wi_b,
                                           xbuf, kkbuf, wilog);
  k_mega<<<NB, 1024, 0, stream>>>(noise, mu, sigma, xbuf, kkbuf, wilog,
                                  Wq, Wk, Wv, gwih, gwhh, gbih, gbhh,
                                  fc1w, fc1b, fc2w, fc2b,
                                  lns_g, lns_b, lnf_g, lnf_b, ws_w, ws_b,
                                  out_slots, out_pos, out_attn);
}